// Round 1
// baseline (1634.990 us; speedup 1.0000x reference)
//
#include <hip/hip_runtime.h>
#include <hip/hip_bf16.h>

#define DMODEL 2048
#define NHEADS 16
#define NKV 4
#define HD 128
#define SEQ 2048
#define BATCH 4

typedef __attribute__((ext_vector_type(4))) float f32x4;
typedef __attribute__((ext_vector_type(8))) short bf16x8;

static __device__ __forceinline__ float bf2f(short u) {
    unsigned int x = ((unsigned int)(unsigned short)u) << 16;
    return __builtin_bit_cast(float, x);
}
static __device__ __forceinline__ short f2bf(float f) {
    unsigned int x = __builtin_bit_cast(unsigned int, f);
    unsigned int r = (x + 0x7fffu + ((x >> 16) & 1u)) >> 16;
    return (short)r;
}

// ---------------- GEMM: C[M,N] = A[M,K] @ B[K,N], bf16 MFMA ----------------
// A source: f32 (A_F32) or bf16(short); B source: f32 weights; C: f32 or bf16.
template <bool A_F32, bool C_F32>
__global__ __launch_bounds__(256)
void gemm_kernel(const void* __restrict__ Ap, const float* __restrict__ Bp,
                 void* __restrict__ Cp, int M, int N, int K) {
    const int BK = 32, PAD = 8, LDT = BK + PAD;  // 40 shorts, 80B row stride
    __shared__ short As[128 * LDT];
    __shared__ short Bt[128 * LDT];  // [col][k] transposed

    const int tid = threadIdx.x;
    const int lane = tid & 63, w = tid >> 6;
    const int wr = w >> 1, wc = w & 1;
    const int lr = lane & 15, lg = lane >> 4;
    const int m0 = blockIdx.y * 128, n0 = blockIdx.x * 128;

    f32x4 acc[4][4] = {};

    for (int k0 = 0; k0 < K; k0 += BK) {
        __syncthreads();
        // stage A tile 128x32 -> As[row][k]
        for (int it = 0; it < 4; ++it) {
            int row = (tid >> 3) + it * 32;
            int kk = (tid & 7) * 4;
            short4 o;
            if (A_F32) {
                const float* A = (const float*)Ap;
                float4 t = *(const float4*)&A[(size_t)(m0 + row) * K + k0 + kk];
                o.x = f2bf(t.x); o.y = f2bf(t.y); o.z = f2bf(t.z); o.w = f2bf(t.w);
            } else {
                const short* A = (const short*)Ap;
                o = *(const short4*)&A[(size_t)(m0 + row) * K + k0 + kk];
            }
            *(short4*)&As[row * LDT + kk] = o;
        }
        // stage B tile 32x128 transposed -> Bt[col][k]
        for (int it = 0; it < 4; ++it) {
            int krow = (tid >> 5) + it * 8;
            int col = (tid & 31) * 4;
            float4 t = *(const float4*)&Bp[(size_t)(k0 + krow) * N + n0 + col];
            Bt[(col + 0) * LDT + krow] = f2bf(t.x);
            Bt[(col + 1) * LDT + krow] = f2bf(t.y);
            Bt[(col + 2) * LDT + krow] = f2bf(t.z);
            Bt[(col + 3) * LDT + krow] = f2bf(t.w);
        }
        __syncthreads();

        bf16x8 af[4], bfr[4];
        for (int rb = 0; rb < 4; ++rb)
            af[rb] = *(const bf16x8*)&As[(wr * 64 + rb * 16 + lr) * LDT + lg * 8];
        for (int cb = 0; cb < 4; ++cb)
            bfr[cb] = *(const bf16x8*)&Bt[(wc * 64 + cb * 16 + lr) * LDT + lg * 8];
        for (int rb = 0; rb < 4; ++rb)
            for (int cb = 0; cb < 4; ++cb)
                acc[rb][cb] = __builtin_amdgcn_mfma_f32_16x16x32_bf16(
                    af[rb], bfr[cb], acc[rb][cb], 0, 0, 0);
    }

    for (int rb = 0; rb < 4; ++rb)
        for (int cb = 0; cb < 4; ++cb)
            for (int j = 0; j < 4; ++j) {
                int row = m0 + wr * 64 + rb * 16 + lg * 4 + j;
                int col = n0 + wc * 64 + cb * 16 + lr;
                float v = acc[rb][cb][j];
                if (C_F32) ((float*)Cp)[(size_t)row * N + col] = v;
                else ((short*)Cp)[(size_t)row * N + col] = f2bf(v);
            }
}

// ---------------- RoPE in-place on bf16 Q and K ----------------
__global__ __launch_bounds__(256)
void rope_kernel(short* __restrict__ Qb, short* __restrict__ Kb) {
    const int QP = BATCH * SEQ * NHEADS * (HD / 2);
    const int KP = BATCH * SEQ * NKV * (HD / 2);
    const int total = QP + KP;
    for (int idx = blockIdx.x * blockDim.x + threadIdx.x; idx < total;
         idx += gridDim.x * blockDim.x) {
        short* base;
        size_t off;
        int i, row;
        if (idx < QP) {
            int t = idx;
            i = t & 63; t >>= 6;
            int hh = t & (NHEADS - 1); t >>= 4;
            row = t;
            base = Qb;
            off = (size_t)row * DMODEL + hh * HD;
        } else {
            int t = idx - QP;
            i = t & 63; t >>= 6;
            int hh = t & (NKV - 1); t >>= 2;
            row = t;
            base = Kb;
            off = (size_t)row * (NKV * HD) + hh * HD;
        }
        int pos = row & (SEQ - 1);
        // inv_freq = 10000^(-i/64) = 2^(-i*log2(10000)/64)
        float invf = exp2f(-(float)i * (13.287712379549449f / 64.0f));
        float ang = (float)pos * invf;
        float s, c;
        sincosf(ang, &s, &c);
        float t1 = bf2f(base[off + i]);
        float t2 = bf2f(base[off + i + 64]);
        base[off + i] = f2bf(t1 * c - t2 * s);
        base[off + i + 64] = f2bf(t2 * c + t1 * s);
    }
}

// ---------------- Flash-style causal GQA attention ----------------
// grid: (S/64, NHEADS, BATCH); 256 thr = 4 waves, wave w owns Q rows [q0+16w, +16)
__global__ __launch_bounds__(256)
void attn_kernel(const short* __restrict__ Q, const short* __restrict__ K,
                 const short* __restrict__ V, short* __restrict__ O) {
    const int KT = 64;
    const int LDK = HD + 8;  // 136 shorts
    const int LDV = KT + 8;  // 72 shorts
    __shared__ short Ks[KT * LDK];
    __shared__ short Vt[HD * LDV];       // [d][kv]
    __shared__ short Pw[4][16 * LDV];    // per-wave P tile [qrow][kv]

    const int tid = threadIdx.x, lane = tid & 63, w = tid >> 6;
    const int lr = lane & 15, lg = lane >> 4;
    const int qt = blockIdx.x, h = blockIdx.y, b = blockIdx.z;
    const int kvh = h >> 2;  // G = 4
    const int q0 = qt * 64;
    const size_t qbase = (size_t)b * SEQ * DMODEL;
    const size_t kbase = (size_t)b * SEQ * (NKV * HD);
    const float scale = 0.08838834764831845f;  // 1/sqrt(128)

    // Q fragments (rows q0+16w+lr)
    bf16x8 qf[4];
    {
        int qrow = q0 + w * 16 + lr;
        for (int kc = 0; kc < 4; ++kc)
            qf[kc] = *(const bf16x8*)&Q[qbase + (size_t)qrow * DMODEL + h * HD + kc * 32 + lg * 8];
    }

    f32x4 oacc[8] = {};
    float mrun[4] = {-__builtin_inff(), -__builtin_inff(), -__builtin_inff(), -__builtin_inff()};
    float lrun[4] = {0.f, 0.f, 0.f, 0.f};

    const int ntiles = qt + 1;
    for (int t = 0; t < ntiles; ++t) {
        const int kv0 = t * KT;
        __syncthreads();
        // stage K tile [64][128] and V transposed [128][64]
        for (int it = 0; it < 4; ++it) {
            int row = (tid >> 4) + it * 16;
            int cc = (tid & 15) * 8;
            bf16x8 kk = *(const bf16x8*)&K[kbase + (size_t)(kv0 + row) * (NKV * HD) + kvh * HD + cc];
            *(bf16x8*)&Ks[row * LDK + cc] = kk;
            bf16x8 vv = *(const bf16x8*)&V[kbase + (size_t)(kv0 + row) * (NKV * HD) + kvh * HD + cc];
            for (int e = 0; e < 8; ++e) Vt[(cc + e) * LDV + row] = vv[e];
        }
        __syncthreads();

        // QK^T -> sacc[cb] covers cols kv0+16cb..+16
        f32x4 sacc[4] = {};
        for (int cb = 0; cb < 4; ++cb)
            for (int kc = 0; kc < 4; ++kc) {
                bf16x8 kf = *(const bf16x8*)&Ks[(cb * 16 + lr) * LDK + kc * 32 + lg * 8];
                sacc[cb] = __builtin_amdgcn_mfma_f32_16x16x32_bf16(qf[kc], kf, sacc[cb], 0, 0, 0);
            }

        // online softmax (rows: q0+16w+4lg+j, cols: kv0+16cb+lr)
        float st[4][4], mnew[4];
        for (int j = 0; j < 4; ++j) mnew[j] = mrun[j];
        for (int cb = 0; cb < 4; ++cb) {
            int col = kv0 + cb * 16 + lr;
            for (int j = 0; j < 4; ++j) {
                int qrow = q0 + w * 16 + lg * 4 + j;
                float s = sacc[cb][j] * scale;
                if (t == ntiles - 1 && col > qrow) s = -__builtin_inff();
                st[cb][j] = s;
                mnew[j] = fmaxf(mnew[j], s);
            }
        }
        for (int mask = 1; mask < 16; mask <<= 1)
            for (int j = 0; j < 4; ++j)
                mnew[j] = fmaxf(mnew[j], __shfl_xor(mnew[j], mask, 64));

        float alpha[4], rs[4];
        for (int j = 0; j < 4; ++j) { alpha[j] = __expf(mrun[j] - mnew[j]); rs[j] = 0.f; }
        short pb[4][4];
        for (int cb = 0; cb < 4; ++cb)
            for (int j = 0; j < 4; ++j) {
                float p = __expf(st[cb][j] - mnew[j]);
                rs[j] += p;
                pb[cb][j] = f2bf(p);
            }
        for (int mask = 1; mask < 16; mask <<= 1)
            for (int j = 0; j < 4; ++j) rs[j] += __shfl_xor(rs[j], mask, 64);
        for (int j = 0; j < 4; ++j) {
            lrun[j] = lrun[j] * alpha[j] + rs[j];
            mrun[j] = mnew[j];
        }
        for (int db = 0; db < 8; ++db) {
            f32x4 o = oacc[db];
            for (int j = 0; j < 4; ++j) o[j] *= alpha[j];
            oacc[db] = o;
        }

        // P -> per-wave LDS, re-read as A-fragments
        for (int cb = 0; cb < 4; ++cb)
            for (int j = 0; j < 4; ++j)
                Pw[w][(lg * 4 + j) * LDV + cb * 16 + lr] = pb[cb][j];
        asm volatile("s_waitcnt lgkmcnt(0)" ::: "memory");
        __builtin_amdgcn_sched_barrier(0);
        bf16x8 pf[2];
        for (int kc = 0; kc < 2; ++kc)
            pf[kc] = *(const bf16x8*)&Pw[w][lr * LDV + kc * 32 + lg * 8];

        // PV: oacc[db] += P @ V  (B-frag from Vt: contiguous along kv)
        for (int db = 0; db < 8; ++db)
            for (int kc = 0; kc < 2; ++kc) {
                bf16x8 vf = *(const bf16x8*)&Vt[(db * 16 + lr) * LDV + kc * 32 + lg * 8];
                oacc[db] = __builtin_amdgcn_mfma_f32_16x16x32_bf16(pf[kc], vf, oacc[db], 0, 0, 0);
            }
    }

    for (int db = 0; db < 8; ++db)
        for (int j = 0; j < 4; ++j) {
            int qrow = q0 + w * 16 + lg * 4 + j;
            float v = oacc[db][j] / lrun[j];
            O[qbase + (size_t)qrow * DMODEL + h * HD + db * 16 + lr] = f2bf(v);
        }
}

extern "C" void kernel_launch(void* const* d_in, const int* in_sizes, int n_in,
                              void* d_out, int out_size, void* d_ws, size_t ws_size,
                              hipStream_t stream) {
    const float* x = (const float*)d_in[0];
    const float* Wq = (const float*)d_in[1];
    const float* Wk = (const float*)d_in[2];
    const float* Wv = (const float*)d_in[3];
    const float* Wo = (const float*)d_in[4];
    float* out = (float*)d_out;

    const size_t BS = (size_t)BATCH * SEQ;  // 8192
    short* Qb = (short*)d_ws;               // 8192*2048
    short* Kb = Qb + BS * DMODEL;           // 8192*512
    short* Vb = Kb + BS * (NKV * HD);       // 8192*512
    short* AO = Vb + BS * (NKV * HD);       // 8192*2048

    dim3 blk(256);
    gemm_kernel<true, false><<<dim3(16, 64), blk, 0, stream>>>((const void*)x, Wq, (void*)Qb, 8192, 2048, 2048);
    gemm_kernel<true, false><<<dim3(4, 64), blk, 0, stream>>>((const void*)x, Wk, (void*)Kb, 8192, 512, 2048);
    gemm_kernel<true, false><<<dim3(4, 64), blk, 0, stream>>>((const void*)x, Wv, (void*)Vb, 8192, 512, 2048);
    rope_kernel<<<dim3(4096), blk, 0, stream>>>(Qb, Kb);
    attn_kernel<<<dim3(SEQ / 64, NHEADS, BATCH), blk, 0, stream>>>(Qb, Kb, Vb, AO);
    gemm_kernel<false, true><<<dim3(16, 64), blk, 0, stream>>>((const void*)AO, Wo, (void*)out, 8192, 2048, 2048);
}

// Round 2
// 663.639 us; speedup vs baseline: 2.4637x; 2.4637x over previous
//
#include <hip/hip_runtime.h>
#include <hip/hip_bf16.h>

#define DMODEL 2048
#define NHEADS 16
#define NKV 4
#define HD 128
#define SEQ 2048
#define BATCH 4

typedef __attribute__((ext_vector_type(4))) float f32x4;
typedef __attribute__((ext_vector_type(8))) short bf16x8;

static __device__ __forceinline__ float bf2f(short u) {
    unsigned int x = ((unsigned int)(unsigned short)u) << 16;
    return __builtin_bit_cast(float, x);
}
static __device__ __forceinline__ short f2bf(float f) {
    unsigned int x = __builtin_bit_cast(unsigned int, f);
    unsigned int r = (x + 0x7fffu + ((x >> 16) & 1u)) >> 16;
    return (short)r;
}
static __device__ __forceinline__ void gload16(const void* g, void* l) {
    __builtin_amdgcn_global_load_lds((const __attribute__((address_space(1))) void*)g,
                                     (__attribute__((address_space(3))) void*)l, 16, 0, 0);
}

// ---------------- f32 -> bf16 row-major convert ----------------
__global__ __launch_bounds__(256)
void conv_x(const float* __restrict__ in, short* __restrict__ out, int n8) {
    for (int i = blockIdx.x * blockDim.x + threadIdx.x; i < n8;
         i += gridDim.x * blockDim.x) {
        float4 a = ((const float4*)in)[(size_t)i * 2];
        float4 b = ((const float4*)in)[(size_t)i * 2 + 1];
        bf16x8 o;
        o[0] = f2bf(a.x); o[1] = f2bf(a.y); o[2] = f2bf(a.z); o[3] = f2bf(a.w);
        o[4] = f2bf(b.x); o[5] = f2bf(b.y); o[6] = f2bf(b.z); o[7] = f2bf(b.w);
        ((bf16x8*)out)[i] = o;
    }
}

// ---------------- transpose-convert: W[R][C] f32 -> Wt[C][R] bf16 ----------------
__global__ __launch_bounds__(256)
void tkern(const float* __restrict__ W, short* __restrict__ Wt, int R, int C) {
    __shared__ short Ts[64 * 72];  // [col][row]
    const int tid = threadIdx.x;
    const int r0 = blockIdx.y * 64, c0 = blockIdx.x * 64;
    for (int it = 0; it < 4; ++it) {
        int idx = it * 256 + tid;
        int row = idx >> 4, col4 = (idx & 15) * 4;
        float4 t = *(const float4*)&W[(size_t)(r0 + row) * C + c0 + col4];
        Ts[(col4 + 0) * 72 + row] = f2bf(t.x);
        Ts[(col4 + 1) * 72 + row] = f2bf(t.y);
        Ts[(col4 + 2) * 72 + row] = f2bf(t.z);
        Ts[(col4 + 3) * 72 + row] = f2bf(t.w);
    }
    __syncthreads();
    for (int it = 0; it < 2; ++it) {
        int idx = it * 256 + tid;
        int n = idx >> 3, k8 = (idx & 7) * 8;
        bf16x8 o = *(const bf16x8*)&Ts[n * 72 + k8];
        *(bf16x8*)&Wt[(size_t)(c0 + n) * R + r0 + k8] = o;
    }
}

// ---------------- bf16 GEMM, m97 structure: C[M,N] = A[M,K] @ Bt[N,K]^T ----------------
template <bool C_F32>
__global__ __launch_bounds__(256)
void gemm_bt(const short* __restrict__ A, const short* __restrict__ B,
             void* __restrict__ Cp, int M, int N, int K) {
    __shared__ short As[128 * 64];
    __shared__ short Bs[128 * 64];
    const int tid = threadIdx.x, lane = tid & 63, w = tid >> 6;
    const int wr = w >> 1, wc = w & 1, lr = lane & 15, lg = lane >> 4;
    const int m0 = blockIdx.y * 128, n0 = blockIdx.x * 128;
    const int l8 = lane >> 3, l7 = lane & 7;
    f32x4 acc[4][4] = {};

    for (int k0 = 0; k0 < K; k0 += 64) {
        __syncthreads();
        for (int it = 0; it < 4; ++it) {
            int row = w * 32 + it * 8 + l8;
            gload16(&A[(size_t)(m0 + row) * K + k0 + l7 * 8], &As[(w * 32 + it * 8) * 64]);
            gload16(&B[(size_t)(n0 + row) * K + k0 + l7 * 8], &Bs[(w * 32 + it * 8) * 64]);
        }
        __syncthreads();
        for (int kc = 0; kc < 2; ++kc) {
            bf16x8 af[4], bfr[4];
            for (int rb = 0; rb < 4; ++rb)
                af[rb] = *(const bf16x8*)&As[(wr * 64 + rb * 16 + lr) * 64 + kc * 32 + lg * 8];
            for (int cb = 0; cb < 4; ++cb)
                bfr[cb] = *(const bf16x8*)&Bs[(wc * 64 + cb * 16 + lr) * 64 + kc * 32 + lg * 8];
            __builtin_amdgcn_s_setprio(1);
            for (int rb = 0; rb < 4; ++rb)
                for (int cb = 0; cb < 4; ++cb)
                    acc[rb][cb] = __builtin_amdgcn_mfma_f32_16x16x32_bf16(
                        af[rb], bfr[cb], acc[rb][cb], 0, 0, 0);
            __builtin_amdgcn_s_setprio(0);
        }
    }

    for (int rb = 0; rb < 4; ++rb)
        for (int cb = 0; cb < 4; ++cb)
            for (int j = 0; j < 4; ++j) {
                int row = m0 + wr * 64 + rb * 16 + lg * 4 + j;
                int col = n0 + wc * 64 + cb * 16 + lr;
                float v = acc[rb][cb][j];
                if (C_F32) ((float*)Cp)[(size_t)row * N + col] = v;
                else ((short*)Cp)[(size_t)row * N + col] = f2bf(v);
            }
}

// ---------------- fallback GEMM (round-1): f32 inputs, convert in-kernel ----------------
template <bool A_F32, bool C_F32>
__global__ __launch_bounds__(256)
void gemm_kernel(const void* __restrict__ Ap, const float* __restrict__ Bp,
                 void* __restrict__ Cp, int M, int N, int K) {
    const int BK = 32, PAD = 8, LDT = BK + PAD;
    __shared__ short As[128 * LDT];
    __shared__ short Bt[128 * LDT];
    const int tid = threadIdx.x;
    const int lane = tid & 63, w = tid >> 6;
    const int wr = w >> 1, wc = w & 1;
    const int lr = lane & 15, lg = lane >> 4;
    const int m0 = blockIdx.y * 128, n0 = blockIdx.x * 128;
    f32x4 acc[4][4] = {};

    for (int k0 = 0; k0 < K; k0 += BK) {
        __syncthreads();
        for (int it = 0; it < 4; ++it) {
            int row = (tid >> 3) + it * 32;
            int kk = (tid & 7) * 4;
            short4 o;
            if (A_F32) {
                const float* A = (const float*)Ap;
                float4 t = *(const float4*)&A[(size_t)(m0 + row) * K + k0 + kk];
                o.x = f2bf(t.x); o.y = f2bf(t.y); o.z = f2bf(t.z); o.w = f2bf(t.w);
            } else {
                const short* A = (const short*)Ap;
                o = *(const short4*)&A[(size_t)(m0 + row) * K + k0 + kk];
            }
            *(short4*)&As[row * LDT + kk] = o;
        }
        for (int it = 0; it < 4; ++it) {
            int krow = (tid >> 5) + it * 8;
            int col = (tid & 31) * 4;
            float4 t = *(const float4*)&Bp[(size_t)(k0 + krow) * N + n0 + col];
            Bt[(col + 0) * LDT + krow] = f2bf(t.x);
            Bt[(col + 1) * LDT + krow] = f2bf(t.y);
            Bt[(col + 2) * LDT + krow] = f2bf(t.z);
            Bt[(col + 3) * LDT + krow] = f2bf(t.w);
        }
        __syncthreads();
        bf16x8 af[4], bfr[4];
        for (int rb = 0; rb < 4; ++rb)
            af[rb] = *(const bf16x8*)&As[(wr * 64 + rb * 16 + lr) * LDT + lg * 8];
        for (int cb = 0; cb < 4; ++cb)
            bfr[cb] = *(const bf16x8*)&Bt[(wc * 64 + cb * 16 + lr) * LDT + lg * 8];
        for (int rb = 0; rb < 4; ++rb)
            for (int cb = 0; cb < 4; ++cb)
                acc[rb][cb] = __builtin_amdgcn_mfma_f32_16x16x32_bf16(
                    af[rb], bfr[cb], acc[rb][cb], 0, 0, 0);
    }

    for (int rb = 0; rb < 4; ++rb)
        for (int cb = 0; cb < 4; ++cb)
            for (int j = 0; j < 4; ++j) {
                int row = m0 + wr * 64 + rb * 16 + lg * 4 + j;
                int col = n0 + wc * 64 + cb * 16 + lr;
                float v = acc[rb][cb][j];
                if (C_F32) ((float*)Cp)[(size_t)row * N + col] = v;
                else ((short*)Cp)[(size_t)row * N + col] = f2bf(v);
            }
}

// ---------------- RoPE in-place on bf16 Q and K (parametrized strides) ----------------
__global__ __launch_bounds__(256)
void rope_kernel(short* __restrict__ Qp, int ldq, short* __restrict__ Kp, int ldk) {
    const int QP = BATCH * SEQ * NHEADS * 64;
    const int KP = BATCH * SEQ * NKV * 64;
    const int total = QP + KP;
    for (int idx = blockIdx.x * blockDim.x + threadIdx.x; idx < total;
         idx += gridDim.x * blockDim.x) {
        short* base;
        size_t off;
        int i, row;
        if (idx < QP) {
            i = idx & 63;
            int hh = (idx >> 6) & (NHEADS - 1);
            row = idx >> 10;
            base = Qp;
            off = (size_t)row * ldq + hh * HD;
        } else {
            int t = idx - QP;
            i = t & 63;
            int hh = (t >> 6) & (NKV - 1);
            row = t >> 8;
            base = Kp;
            off = (size_t)row * ldk + hh * HD;
        }
        int pos = row & (SEQ - 1);
        float invf = exp2f(-(float)i * (13.287712379549449f / 64.0f));
        float ang = (float)pos * invf;
        float s, c;
        sincosf(ang, &s, &c);
        float t1 = bf2f(base[off + i]);
        float t2 = bf2f(base[off + i + 64]);
        base[off + i] = f2bf(t1 * c - t2 * s);
        base[off + i + 64] = f2bf(t2 * c + t1 * s);
    }
}

// ---------------- Flash-style causal GQA attention (swizzled LDS) ----------------
// Ks: (r,c) -> r*128 + ((c>>3 ^ (r&7))<<3) + (c&7)     [16 KB]
// Vt: (d,kv)-> d*64 + ((kv>>3 ^ g(d))<<3) + (kv&7), g(d)=(d^(d>>3))&7   [16 KB]
// Pw: per-wave (q,kv) -> w*1024 + q*64 + ((kv>>3 ^ (q&7))<<3) + (kv&7)  [8 KB]
__global__ __launch_bounds__(256)
void attn_kernel(const short* __restrict__ Qp, int ldq,
                 const short* __restrict__ Kp, int ldk,
                 const short* __restrict__ Vp, int ldv,
                 short* __restrict__ O) {
    __shared__ short Ks[64 * 128];
    __shared__ short Vt[128 * 64];
    __shared__ short Pw[4 * 16 * 64];

    const int tid = threadIdx.x, lane = tid & 63, w = tid >> 6;
    const int lr = lane & 15, lg = lane >> 4;
    const int qt = blockIdx.x, h = blockIdx.y, b = blockIdx.z;
    const int kvh = h >> 2;
    const int q0 = qt * 64;
    const size_t brow = (size_t)b * SEQ;
    const float scale = 0.08838834764831845f;  // 1/sqrt(128)

    bf16x8 qf[4];
    {
        int qrow = q0 + w * 16 + lr;
        for (int kc = 0; kc < 4; ++kc)
            qf[kc] = *(const bf16x8*)&Qp[(brow + qrow) * ldq + h * HD + kc * 32 + lg * 8];
    }

    f32x4 oacc[8] = {};
    float mrun[4], lrun[4];
    for (int j = 0; j < 4; ++j) { mrun[j] = -__builtin_inff(); lrun[j] = 0.f; }

    const int ntiles = qt + 1;
    for (int t = 0; t < ntiles; ++t) {
        const int kv0 = t * 64;
        __syncthreads();
        // K tile via global_load_lds with pre-swizzled source (linear LDS dest)
        for (int it = 0; it < 4; ++it) {
            int row = w * 16 + it * 4 + (lane >> 4);
            int cblk = (lane & 15) ^ (row & 7);
            gload16(&Kp[(brow + kv0 + row) * ldk + kvh * HD + cblk * 8],
                    &Ks[(w * 16 + it * 4) * 128]);
        }
        // V tile: reg-staged transpose with swizzled scatter (~2-way conflicts)
        for (int it = 0; it < 4; ++it) {
            int rv = (tid >> 4) + it * 16;
            int d0 = (tid & 15) * 8;
            bf16x8 vv = *(const bf16x8*)&Vp[(brow + kv0 + rv) * ldv + kvh * HD + d0];
            for (int e = 0; e < 8; ++e) {
                int d = d0 + e;
                int g = (d ^ (d >> 3)) & 7;
                Vt[d * 64 + (((rv >> 3) ^ g) << 3) + (rv & 7)] = vv[e];
            }
        }
        __syncthreads();

        // QK^T
        f32x4 sacc[4] = {};
        __builtin_amdgcn_s_setprio(1);
        for (int cb = 0; cb < 4; ++cb)
            for (int kc = 0; kc < 4; ++kc) {
                bf16x8 kf = *(const bf16x8*)&Ks[(cb * 16 + lr) * 128 +
                                                (((kc * 4 + lg) ^ (lr & 7)) << 3)];
                sacc[cb] = __builtin_amdgcn_mfma_f32_16x16x32_bf16(qf[kc], kf, sacc[cb], 0, 0, 0);
            }
        __builtin_amdgcn_s_setprio(0);

        // online softmax
        float st[4][4], mnew[4];
        for (int j = 0; j < 4; ++j) mnew[j] = mrun[j];
        for (int cb = 0; cb < 4; ++cb) {
            int col = kv0 + cb * 16 + lr;
            for (int j = 0; j < 4; ++j) {
                int qrow = q0 + w * 16 + lg * 4 + j;
                float s = sacc[cb][j] * scale;
                if (t == ntiles - 1 && col > qrow) s = -__builtin_inff();
                st[cb][j] = s;
                mnew[j] = fmaxf(mnew[j], s);
            }
        }
        for (int mask = 1; mask < 16; mask <<= 1)
            for (int j = 0; j < 4; ++j)
                mnew[j] = fmaxf(mnew[j], __shfl_xor(mnew[j], mask, 64));

        float alpha[4], rs[4];
        for (int j = 0; j < 4; ++j) { alpha[j] = __expf(mrun[j] - mnew[j]); rs[j] = 0.f; }
        short pb[4][4];
        for (int cb = 0; cb < 4; ++cb)
            for (int j = 0; j < 4; ++j) {
                float p = __expf(st[cb][j] - mnew[j]);
                rs[j] += p;
                pb[cb][j] = f2bf(p);
            }
        for (int mask = 1; mask < 16; mask <<= 1)
            for (int j = 0; j < 4; ++j) rs[j] += __shfl_xor(rs[j], mask, 64);
        for (int j = 0; j < 4; ++j) {
            lrun[j] = lrun[j] * alpha[j] + rs[j];
            mrun[j] = mnew[j];
        }
        for (int db = 0; db < 8; ++db) {
            f32x4 o = oacc[db];
            for (int j = 0; j < 4; ++j) o[j] *= alpha[j];
            oacc[db] = o;
        }

        // P -> per-wave LDS (swizzled), re-read as A-fragments
        for (int cb = 0; cb < 4; ++cb)
            for (int j = 0; j < 4; ++j) {
                int q = lg * 4 + j;
                Pw[w * 1024 + q * 64 + (((cb * 2 + (lr >> 3)) ^ (q & 7)) << 3) + (lr & 7)] =
                    pb[cb][j];
            }
        asm volatile("s_waitcnt lgkmcnt(0)" ::: "memory");
        __builtin_amdgcn_sched_barrier(0);
        bf16x8 pf[2];
        for (int kc = 0; kc < 2; ++kc)
            pf[kc] = *(const bf16x8*)&Pw[w * 1024 + lr * 64 +
                                         (((kc * 4 + lg) ^ (lr & 7)) << 3)];

        // PV
        __builtin_amdgcn_s_setprio(1);
        for (int db = 0; db < 8; ++db)
            for (int kc = 0; kc < 2; ++kc) {
                int d = db * 16 + lr;
                int g = (d ^ (d >> 3)) & 7;
                bf16x8 vf = *(const bf16x8*)&Vt[d * 64 + (((kc * 4 + lg) ^ g) << 3)];
                oacc[db] = __builtin_amdgcn_mfma_f32_16x16x32_bf16(pf[kc], vf, oacc[db], 0, 0, 0);
            }
        __builtin_amdgcn_s_setprio(0);
    }

    for (int db = 0; db < 8; ++db)
        for (int j = 0; j < 4; ++j) {
            int qrow = q0 + w * 16 + lg * 4 + j;
            O[(brow + qrow) * DMODEL + h * HD + db * 16 + lr] = f2bf(oacc[db][j] / lrun[j]);
        }
}

extern "C" void kernel_launch(void* const* d_in, const int* in_sizes, int n_in,
                              void* d_out, int out_size, void* d_ws, size_t ws_size,
                              hipStream_t stream) {
    const float* x = (const float*)d_in[0];
    const float* Wq = (const float*)d_in[1];
    const float* Wk = (const float*)d_in[2];
    const float* Wv = (const float*)d_in[3];
    const float* Wo = (const float*)d_in[4];
    float* out = (float*)d_out;

    const size_t BS = (size_t)BATCH * SEQ;  // 8192
    dim3 blk(256);

    const size_t planA_shorts = BS * 2048 + BS * 3072 + (size_t)3072 * 2048 + (size_t)2048 * 2048;
    if (ws_size >= planA_shorts * 2) {
        // Plan A: bf16 precast + fused QKV GEMM + m97-structure GEMMs
        short* xb = (short*)d_ws;                    // [8192][2048] bf16 (later reused as AO)
        short* QKV = xb + BS * 2048;                 // [8192][3072]: Q | K | V
        short* WqkvT = QKV + BS * 3072;              // [3072][2048]
        short* WoT = WqkvT + (size_t)3072 * 2048;    // [2048][2048]
        short* AO = xb;

        conv_x<<<dim3(2048), blk, 0, stream>>>(x, xb, (int)(BS * 2048 / 8));
        tkern<<<dim3(32, 32), blk, 0, stream>>>(Wq, WqkvT, 2048, 2048);
        tkern<<<dim3(8, 32), blk, 0, stream>>>(Wk, WqkvT + (size_t)2048 * 2048, 2048, 512);
        tkern<<<dim3(8, 32), blk, 0, stream>>>(Wv, WqkvT + (size_t)2560 * 2048, 2048, 512);
        tkern<<<dim3(32, 32), blk, 0, stream>>>(Wo, WoT, 2048, 2048);
        gemm_bt<false><<<dim3(24, 64), blk, 0, stream>>>(xb, WqkvT, (void*)QKV, 8192, 3072, 2048);
        rope_kernel<<<dim3(4096), blk, 0, stream>>>(QKV, 3072, QKV + 2048, 3072);
        attn_kernel<<<dim3(SEQ / 64, NHEADS, BATCH), blk, 0, stream>>>(
            QKV, 3072, QKV + 2048, 3072, QKV + 2560, 3072, AO);
        gemm_bt<true><<<dim3(16, 64), blk, 0, stream>>>(AO, WoT, (void*)out, 8192, 2048, 2048);
    } else {
        // Plan B: round-1 structure (f32 convert inside GEMM)
        short* Qb = (short*)d_ws;
        short* Kb = Qb + BS * DMODEL;
        short* Vb = Kb + BS * (NKV * HD);
        short* AO = Vb + BS * (NKV * HD);
        gemm_kernel<true, false><<<dim3(16, 64), blk, 0, stream>>>((const void*)x, Wq, (void*)Qb, 8192, 2048, 2048);
        gemm_kernel<true, false><<<dim3(4, 64), blk, 0, stream>>>((const void*)x, Wk, (void*)Kb, 8192, 512, 2048);
        gemm_kernel<true, false><<<dim3(4, 64), blk, 0, stream>>>((const void*)x, Wv, (void*)Vb, 8192, 512, 2048);
        rope_kernel<<<dim3(4096), blk, 0, stream>>>(Qb, 2048, Kb, 512);
        attn_kernel<<<dim3(SEQ / 64, NHEADS, BATCH), blk, 0, stream>>>(
            Qb, 2048, Kb, 512, Vb, 512, AO);
        gemm_kernel<false, true><<<dim3(16, 64), blk, 0, stream>>>((const void*)AO, Wo, (void*)out, 8192, 2048, 2048);
    }
}

// Round 3
// 535.555 us; speedup vs baseline: 3.0529x; 1.2392x over previous
//
#include <hip/hip_runtime.h>
#include <hip/hip_bf16.h>

#define DMODEL 2048
#define NHEADS 16
#define NKV 4
#define HD 128
#define SEQ 2048
#define BATCH 4

typedef __attribute__((ext_vector_type(4))) float f32x4;
typedef __attribute__((ext_vector_type(8))) short bf16x8;

static __device__ __forceinline__ float bf2f(short u) {
    unsigned int x = ((unsigned int)(unsigned short)u) << 16;
    return __builtin_bit_cast(float, x);
}
static __device__ __forceinline__ short f2bf(float f) {
    unsigned int x = __builtin_bit_cast(unsigned int, f);
    unsigned int r = (x + 0x7fffu + ((x >> 16) & 1u)) >> 16;
    return (short)r;
}
static __device__ __forceinline__ void gload16(const void* g, void* l) {
    __builtin_amdgcn_global_load_lds((const __attribute__((address_space(1))) void*)g,
                                     (__attribute__((address_space(3))) void*)l, 16, 0, 0);
}

// ---------------- f32 -> bf16 row-major convert ----------------
__global__ __launch_bounds__(256)
void conv_x(const float* __restrict__ in, short* __restrict__ out, int n8) {
    for (int i = blockIdx.x * blockDim.x + threadIdx.x; i < n8;
         i += gridDim.x * blockDim.x) {
        float4 a = ((const float4*)in)[(size_t)i * 2];
        float4 b = ((const float4*)in)[(size_t)i * 2 + 1];
        bf16x8 o;
        o[0] = f2bf(a.x); o[1] = f2bf(a.y); o[2] = f2bf(a.z); o[3] = f2bf(a.w);
        o[4] = f2bf(b.x); o[5] = f2bf(b.y); o[6] = f2bf(b.z); o[7] = f2bf(b.w);
        ((bf16x8*)out)[i] = o;
    }
}

// ---------------- transpose-convert: W[R][C] f32 -> Wt[C][R] bf16 ----------------
__global__ __launch_bounds__(256)
void tkern(const float* __restrict__ W, short* __restrict__ Wt, int R, int C) {
    __shared__ short Ts[64 * 72];
    const int tid = threadIdx.x;
    const int r0 = blockIdx.y * 64, c0 = blockIdx.x * 64;
    for (int it = 0; it < 4; ++it) {
        int idx = it * 256 + tid;
        int row = idx >> 4, col4 = (idx & 15) * 4;
        float4 t = *(const float4*)&W[(size_t)(r0 + row) * C + c0 + col4];
        Ts[(col4 + 0) * 72 + row] = f2bf(t.x);
        Ts[(col4 + 1) * 72 + row] = f2bf(t.y);
        Ts[(col4 + 2) * 72 + row] = f2bf(t.z);
        Ts[(col4 + 3) * 72 + row] = f2bf(t.w);
    }
    __syncthreads();
    for (int it = 0; it < 2; ++it) {
        int idx = it * 256 + tid;
        int n = idx >> 3, k8 = (idx & 7) * 8;
        bf16x8 o = *(const bf16x8*)&Ts[n * 72 + k8];
        *(bf16x8*)&Wt[(size_t)(c0 + n) * R + r0 + k8] = o;
    }
}

// ---------------- bf16 GEMM, m97 structure: C[M,N] = A[M,K] @ Bt[N,K]^T ----------------
template <bool C_F32>
__global__ __launch_bounds__(256)
void gemm_bt(const short* __restrict__ A, const short* __restrict__ B,
             void* __restrict__ Cp, int M, int N, int K) {
    __shared__ short As[128 * 64];
    __shared__ short Bs[128 * 64];
    const int tid = threadIdx.x, lane = tid & 63, w = tid >> 6;
    const int wr = w >> 1, wc = w & 1, lr = lane & 15, lg = lane >> 4;
    const int m0 = blockIdx.y * 128, n0 = blockIdx.x * 128;
    const int l8 = lane >> 3, l7 = lane & 7;
    f32x4 acc[4][4] = {};

    for (int k0 = 0; k0 < K; k0 += 64) {
        __syncthreads();
        for (int it = 0; it < 4; ++it) {
            int row = w * 32 + it * 8 + l8;
            gload16(&A[(size_t)(m0 + row) * K + k0 + l7 * 8], &As[(w * 32 + it * 8) * 64]);
            gload16(&B[(size_t)(n0 + row) * K + k0 + l7 * 8], &Bs[(w * 32 + it * 8) * 64]);
        }
        __syncthreads();
        for (int kc = 0; kc < 2; ++kc) {
            bf16x8 af[4], bfr[4];
            for (int rb = 0; rb < 4; ++rb)
                af[rb] = *(const bf16x8*)&As[(wr * 64 + rb * 16 + lr) * 64 + kc * 32 + lg * 8];
            for (int cb = 0; cb < 4; ++cb)
                bfr[cb] = *(const bf16x8*)&Bs[(wc * 64 + cb * 16 + lr) * 64 + kc * 32 + lg * 8];
            __builtin_amdgcn_s_setprio(1);
            for (int rb = 0; rb < 4; ++rb)
                for (int cb = 0; cb < 4; ++cb)
                    acc[rb][cb] = __builtin_amdgcn_mfma_f32_16x16x32_bf16(
                        af[rb], bfr[cb], acc[rb][cb], 0, 0, 0);
            __builtin_amdgcn_s_setprio(0);
        }
    }

    for (int rb = 0; rb < 4; ++rb)
        for (int cb = 0; cb < 4; ++cb)
            for (int j = 0; j < 4; ++j) {
                int row = m0 + wr * 64 + rb * 16 + lg * 4 + j;
                int col = n0 + wc * 64 + cb * 16 + lr;
                float v = acc[rb][cb][j];
                if (C_F32) ((float*)Cp)[(size_t)row * N + col] = v;
                else ((short*)Cp)[(size_t)row * N + col] = f2bf(v);
            }
}

// ---------------- fallback GEMM (round-1): f32 inputs, convert in-kernel ----------------
template <bool A_F32, bool C_F32>
__global__ __launch_bounds__(256)
void gemm_kernel(const void* __restrict__ Ap, const float* __restrict__ Bp,
                 void* __restrict__ Cp, int M, int N, int K) {
    const int BK = 32, PAD = 8, LDT = BK + PAD;
    __shared__ short As[128 * LDT];
    __shared__ short Bt[128 * LDT];
    const int tid = threadIdx.x;
    const int lane = tid & 63, w = tid >> 6;
    const int wr = w >> 1, wc = w & 1;
    const int lr = lane & 15, lg = lane >> 4;
    const int m0 = blockIdx.y * 128, n0 = blockIdx.x * 128;
    f32x4 acc[4][4] = {};

    for (int k0 = 0; k0 < K; k0 += BK) {
        __syncthreads();
        for (int it = 0; it < 4; ++it) {
            int row = (tid >> 3) + it * 32;
            int kk = (tid & 7) * 4;
            short4 o;
            if (A_F32) {
                const float* A = (const float*)Ap;
                float4 t = *(const float4*)&A[(size_t)(m0 + row) * K + k0 + kk];
                o.x = f2bf(t.x); o.y = f2bf(t.y); o.z = f2bf(t.z); o.w = f2bf(t.w);
            } else {
                const short* A = (const short*)Ap;
                o = *(const short4*)&A[(size_t)(m0 + row) * K + k0 + kk];
            }
            *(short4*)&As[row * LDT + kk] = o;
        }
        for (int it = 0; it < 4; ++it) {
            int krow = (tid >> 5) + it * 8;
            int col = (tid & 31) * 4;
            float4 t = *(const float4*)&Bp[(size_t)(k0 + krow) * N + n0 + col];
            Bt[(col + 0) * LDT + krow] = f2bf(t.x);
            Bt[(col + 1) * LDT + krow] = f2bf(t.y);
            Bt[(col + 2) * LDT + krow] = f2bf(t.z);
            Bt[(col + 3) * LDT + krow] = f2bf(t.w);
        }
        __syncthreads();
        bf16x8 af[4], bfr[4];
        for (int rb = 0; rb < 4; ++rb)
            af[rb] = *(const bf16x8*)&As[(wr * 64 + rb * 16 + lr) * LDT + lg * 8];
        for (int cb = 0; cb < 4; ++cb)
            bfr[cb] = *(const bf16x8*)&Bt[(wc * 64 + cb * 16 + lr) * LDT + lg * 8];
        for (int rb = 0; rb < 4; ++rb)
            for (int cb = 0; cb < 4; ++cb)
                acc[rb][cb] = __builtin_amdgcn_mfma_f32_16x16x32_bf16(
                    af[rb], bfr[cb], acc[rb][cb], 0, 0, 0);
    }

    for (int rb = 0; rb < 4; ++rb)
        for (int cb = 0; cb < 4; ++cb)
            for (int j = 0; j < 4; ++j) {
                int row = m0 + wr * 64 + rb * 16 + lg * 4 + j;
                int col = n0 + wc * 64 + cb * 16 + lr;
                float v = acc[rb][cb][j];
                if (C_F32) ((float*)Cp)[(size_t)row * N + col] = v;
                else ((short*)Cp)[(size_t)row * N + col] = f2bf(v);
            }
}

// ---------------- RoPE in-place on bf16 Q and K ----------------
__global__ __launch_bounds__(256)
void rope_kernel(short* __restrict__ Qp, int ldq, short* __restrict__ Kp, int ldk) {
    const int QP = BATCH * SEQ * NHEADS * 64;
    const int KP = BATCH * SEQ * NKV * 64;
    const int total = QP + KP;
    for (int idx = blockIdx.x * blockDim.x + threadIdx.x; idx < total;
         idx += gridDim.x * blockDim.x) {
        short* base;
        size_t off;
        int i, row;
        if (idx < QP) {
            i = idx & 63;
            int hh = (idx >> 6) & (NHEADS - 1);
            row = idx >> 10;
            base = Qp;
            off = (size_t)row * ldq + hh * HD;
        } else {
            int t = idx - QP;
            i = t & 63;
            int hh = (t >> 6) & (NKV - 1);
            row = t >> 8;
            base = Kp;
            off = (size_t)row * ldk + hh * HD;
        }
        int pos = row & (SEQ - 1);
        float invf = exp2f(-(float)i * (13.287712379549449f / 64.0f));
        float ang = (float)pos * invf;
        float s, c;
        sincosf(ang, &s, &c);
        float t1 = bf2f(base[off + i]);
        float t2 = bf2f(base[off + i + 64]);
        base[off + i] = f2bf(t1 * c - t2 * s);
        base[off + i + 64] = f2bf(t2 * c + t1 * s);
    }
}

// ---------------- Flash attention: swapped QK^T, dbuf K/V, async stage ----------------
// Ks[buf]: (r,c8) -> r*128 + ((c8 ^ (r&7))<<3)+c&7    via pre-swizzled gload src
// Vt[buf]: (d,kv) -> d*64 + (((kv>>3)^g(d))<<3)+(kv&7), g(d)=(d^(d>>3))&7
// Pw per-wave: (q,k) -> q*64 + (((k>>3)^(q&7))<<3)+(k&7)
__global__ __launch_bounds__(256)
void attn_kernel(const short* __restrict__ Qp, int ldq,
                 const short* __restrict__ Kp, int ldk,
                 const short* __restrict__ Vp, int ldv,
                 short* __restrict__ O) {
    __shared__ short Ks[2][64 * 128];
    __shared__ short Vt[2][128 * 64];
    __shared__ short Pw[4 * 16 * 64];

    const int tid = threadIdx.x, lane = tid & 63, w = tid >> 6;
    const int lr = lane & 15, lg = lane >> 4;
    const int qt = blockIdx.x, h = blockIdx.y, b = blockIdx.z;
    const int kvh = h >> 2;
    const int q0 = qt * 64;
    const size_t brow = (size_t)b * SEQ;
    const float scale = 0.08838834764831845f;  // 1/sqrt(128)

    // Q fragments for row q0+w*16+lr, pre-scaled by 1/sqrt(hd)
    const int qrow = q0 + w * 16 + lr;
    bf16x8 qf[4];
#pragma unroll
    for (int kc = 0; kc < 4; ++kc) {
        bf16x8 r = *(const bf16x8*)&Qp[(brow + qrow) * ldq + h * HD + kc * 32 + lg * 8];
#pragma unroll
        for (int e = 0; e < 8; ++e) r[e] = f2bf(bf2f(r[e]) * scale);
        qf[kc] = r;
    }

    // V prefetch registers: thread covers rows rv0=(tid>>4)*2+it*32 (+1), cols d0..d0+7
    const int d0 = lr * 8;
    const int rvb = (tid >> 4) * 2;
    bf16x8 vreg[2][2];

    f32x4 oacc[8] = {};
    float mrun = -__builtin_inff(), lrun = 0.f;

    const int ntiles = qt + 1;

    // ---- staging helpers (inlined by unroll) ----
#define STAGE_K(T, BUF)                                                              \
    {                                                                                \
        _Pragma("unroll") for (int it = 0; it < 4; ++it) {                           \
            int row = w * 16 + it * 4 + (lane >> 4);                                 \
            int cblk = (lane & 15) ^ (row & 7);                                      \
            gload16(&Kp[(brow + (size_t)(T) * 64 + row) * ldk + kvh * HD + cblk * 8],\
                    &Ks[BUF][(w * 16 + it * 4) * 128]);                              \
        }                                                                            \
    }
#define LOAD_V(T)                                                                    \
    {                                                                                \
        _Pragma("unroll") for (int it = 0; it < 2; ++it)                             \
            _Pragma("unroll") for (int h2 = 0; h2 < 2; ++h2)                         \
                vreg[it][h2] = *(const bf16x8*)&Vp[(brow + (size_t)(T) * 64 + rvb +  \
                                                    it * 32 + h2) * ldv + kvh * HD + d0];\
    }
#define WRITE_V(BUF)                                                                 \
    {                                                                                \
        _Pragma("unroll") for (int it = 0; it < 2; ++it) {                           \
            int rv0 = rvb + it * 32;                                                 \
            _Pragma("unroll") for (int e = 0; e < 8; ++e) {                          \
                int d = d0 + e;                                                      \
                int g = (e ^ lr) & 7;                                                \
                unsigned int pk = ((unsigned int)(unsigned short)vreg[it][0][e]) |   \
                                  (((unsigned int)(unsigned short)vreg[it][1][e]) << 16);\
                *(unsigned int*)&Vt[BUF][d * 64 + (((rv0 >> 3) ^ g) << 3) + (rv0 & 7)] = pk;\
            }                                                                        \
        }                                                                            \
    }

    // prologue: stage tile 0
    STAGE_K(0, 0);
    LOAD_V(0);
    WRITE_V(0);
    __syncthreads();

    int cur = 0;
    for (int t = 0; t < ntiles; ++t) {
        const int kv0 = t * 64;
        const int nxt = cur ^ 1;
        const bool pre = (t + 1 < ntiles);
        if (pre) {
            if (nxt) { STAGE_K(t + 1, 1); } else { STAGE_K(t + 1, 0); }
            LOAD_V(t + 1);
        }

        // QK^T swapped: sacc[cb][j] = S[q=lr][k=kv0+cb*16+lg*4+j]
        f32x4 sacc[4] = {};
        __builtin_amdgcn_s_setprio(1);
#pragma unroll
        for (int cb = 0; cb < 4; ++cb)
#pragma unroll
            for (int kc = 0; kc < 4; ++kc) {
                bf16x8 kf = *(const bf16x8*)&Ks[cur][(cb * 16 + lr) * 128 +
                                                     (((kc * 4 + lg) ^ (lr & 7)) << 3)];
                sacc[cb] = __builtin_amdgcn_mfma_f32_16x16x32_bf16(kf, qf[kc], sacc[cb], 0, 0, 0);
            }
        __builtin_amdgcn_s_setprio(0);

        // per-lane online softmax (lane owns q-row qrow, 16 k-values)
        float st[16];
#pragma unroll
        for (int cb = 0; cb < 4; ++cb)
#pragma unroll
            for (int j = 0; j < 4; ++j) {
                float s = sacc[cb][j];
                if (t == ntiles - 1) {
                    int col = kv0 + cb * 16 + lg * 4 + j;
                    if (col > qrow) s = -__builtin_inff();
                }
                st[cb * 4 + j] = s;
            }
        float m8[8], m4[4];
#pragma unroll
        for (int i = 0; i < 8; ++i) m8[i] = fmaxf(st[i], st[i + 8]);
#pragma unroll
        for (int i = 0; i < 4; ++i) m4[i] = fmaxf(m8[i], m8[i + 4]);
        float mnew = fmaxf(fmaxf(fmaxf(m4[0], m4[1]), fmaxf(m4[2], m4[3])), mrun);
        mnew = fmaxf(mnew, __shfl_xor(mnew, 16, 64));
        mnew = fmaxf(mnew, __shfl_xor(mnew, 32, 64));

        float alpha = __expf(mrun - mnew);
        float p[16];
#pragma unroll
        for (int i = 0; i < 16; ++i) p[i] = __expf(st[i] - mnew);
        float s8[8], s4[4];
#pragma unroll
        for (int i = 0; i < 8; ++i) s8[i] = p[i] + p[i + 8];
#pragma unroll
        for (int i = 0; i < 4; ++i) s4[i] = s8[i] + s8[i + 4];
        float rs = (s4[0] + s4[1]) + (s4[2] + s4[3]);
        rs += __shfl_xor(rs, 16, 64);
        rs += __shfl_xor(rs, 32, 64);
        lrun = lrun * alpha + rs;
        mrun = mnew;
#pragma unroll
        for (int db = 0; db < 8; ++db) {
            f32x4 o = oacc[db];
#pragma unroll
            for (int j = 0; j < 4; ++j) o[j] *= alpha;
            oacc[db] = o;
        }

        // P^T -> Pw as 4x b64 (k = cb*16+lg*4+j contiguous)
#pragma unroll
        for (int cb = 0; cb < 4; ++cb) {
            unsigned long long pk = 0;
#pragma unroll
            for (int j = 0; j < 4; ++j)
                pk |= ((unsigned long long)(unsigned short)f2bf(p[cb * 4 + j])) << (16 * j);
            int chunk = (cb * 2 + (lg >> 1)) ^ (lr & 7);
            *(unsigned long long*)&Pw[w * 1024 + lr * 64 + (chunk << 3) + (lg & 1) * 4] = pk;
        }
        // read P as B-fragments (compiler inserts lgkmcnt for the RAW dep)
        bf16x8 pf[2];
#pragma unroll
        for (int kc = 0; kc < 2; ++kc)
            pf[kc] = *(const bf16x8*)&Pw[w * 1024 + lr * 64 +
                                         (((kc * 4 + lg) ^ (lr & 7)) << 3)];

        // PV: oacc = V^T(A) @ P(B) -> O^T[d][q=lr]
        __builtin_amdgcn_s_setprio(1);
#pragma unroll
        for (int db = 0; db < 8; ++db)
#pragma unroll
            for (int kc = 0; kc < 2; ++kc) {
                int d = db * 16 + lr;
                int g = ((lr & 7) ^ (db * 2 + (lr >> 3))) & 7;
                bf16x8 vf = *(const bf16x8*)&Vt[cur][d * 64 + (((kc * 4 + lg) ^ g) << 3)];
                oacc[db] = __builtin_amdgcn_mfma_f32_16x16x32_bf16(vf, pf[kc], oacc[db], 0, 0, 0);
            }
        __builtin_amdgcn_s_setprio(0);

        if (pre) { if (nxt) { WRITE_V(1); } else { WRITE_V(0); } }
        __syncthreads();
        cur = nxt;
    }

    // epilogue: O[qrow][d], d = db*16+lg*4+j
    const float invl = 1.0f / lrun;
#pragma unroll
    for (int db = 0; db < 8; ++db) {
        short4 o4;
        o4.x = f2bf(oacc[db][0] * invl);
        o4.y = f2bf(oacc[db][1] * invl);
        o4.z = f2bf(oacc[db][2] * invl);
        o4.w = f2bf(oacc[db][3] * invl);
        *(short4*)&O[(brow + qrow) * DMODEL + h * HD + db * 16 + lg * 4] = o4;
    }
#undef STAGE_K
#undef LOAD_V
#undef WRITE_V
}

extern "C" void kernel_launch(void* const* d_in, const int* in_sizes, int n_in,
                              void* d_out, int out_size, void* d_ws, size_t ws_size,
                              hipStream_t stream) {
    const float* x = (const float*)d_in[0];
    const float* Wq = (const float*)d_in[1];
    const float* Wk = (const float*)d_in[2];
    const float* Wv = (const float*)d_in[3];
    const float* Wo = (const float*)d_in[4];
    float* out = (float*)d_out;

    const size_t BS = (size_t)BATCH * SEQ;  // 8192
    dim3 blk(256);

    const size_t planA_shorts = BS * 2048 + BS * 3072 + (size_t)3072 * 2048 + (size_t)2048 * 2048;
    if (ws_size >= planA_shorts * 2) {
        short* xb = (short*)d_ws;                    // [8192][2048] bf16 (reused as AO)
        short* QKV = xb + BS * 2048;                 // [8192][3072]: Q | K | V
        short* WqkvT = QKV + BS * 3072;              // [3072][2048]
        short* WoT = WqkvT + (size_t)3072 * 2048;    // [2048][2048]
        short* AO = xb;

        conv_x<<<dim3(2048), blk, 0, stream>>>(x, xb, (int)(BS * 2048 / 8));
        tkern<<<dim3(32, 32), blk, 0, stream>>>(Wq, WqkvT, 2048, 2048);
        tkern<<<dim3(8, 32), blk, 0, stream>>>(Wk, WqkvT + (size_t)2048 * 2048, 2048, 512);
        tkern<<<dim3(8, 32), blk, 0, stream>>>(Wv, WqkvT + (size_t)2560 * 2048, 2048, 512);
        tkern<<<dim3(32, 32), blk, 0, stream>>>(Wo, WoT, 2048, 2048);
        gemm_bt<false><<<dim3(24, 64), blk, 0, stream>>>(xb, WqkvT, (void*)QKV, 8192, 3072, 2048);
        rope_kernel<<<dim3(4096), blk, 0, stream>>>(QKV, 3072, QKV + 2048, 3072);
        attn_kernel<<<dim3(SEQ / 64, NHEADS, BATCH), blk, 0, stream>>>(
            QKV, 3072, QKV + 2048, 3072, QKV + 2560, 3072, AO);
        gemm_bt<true><<<dim3(16, 64), blk, 0, stream>>>(AO, WoT, (void*)out, 8192, 2048, 2048);
    } else {
        short* Qb = (short*)d_ws;
        short* Kb = Qb + BS * DMODEL;
        short* Vb = Kb + BS * (NKV * HD);
        short* AO = Vb + BS * (NKV * HD);
        gemm_kernel<true, false><<<dim3(16, 64), blk, 0, stream>>>((const void*)x, Wq, (void*)Qb, 8192, 2048, 2048);
        gemm_kernel<true, false><<<dim3(4, 64), blk, 0, stream>>>((const void*)x, Wk, (void*)Kb, 8192, 512, 2048);
        gemm_kernel<true, false><<<dim3(4, 64), blk, 0, stream>>>((const void*)x, Wv, (void*)Vb, 8192, 512, 2048);
        rope_kernel<<<dim3(4096), blk, 0, stream>>>(Qb, 2048, Kb, 512);
        attn_kernel<<<dim3(SEQ / 64, NHEADS, BATCH), blk, 0, stream>>>(
            Qb, 2048, Kb, 512, Vb, 512, AO);
        gemm_kernel<false, true><<<dim3(16, 64), blk, 0, stream>>>((const void*)AO, Wo, (void*)out, 8192, 2048, 2048);
    }
}

// Round 4
// 519.172 us; speedup vs baseline: 3.1492x; 1.0316x over previous
//
#include <hip/hip_runtime.h>
#include <hip/hip_bf16.h>

#define DMODEL 2048
#define NHEADS 16
#define NKV 4
#define HD 128
#define SEQ 2048
#define BATCH 4

typedef __attribute__((ext_vector_type(4))) float f32x4;
typedef __attribute__((ext_vector_type(8))) short bf16x8;

static __device__ __forceinline__ float bf2f(short u) {
    unsigned int x = ((unsigned int)(unsigned short)u) << 16;
    return __builtin_bit_cast(float, x);
}
static __device__ __forceinline__ short f2bf(float f) {
    unsigned int x = __builtin_bit_cast(unsigned int, f);
    unsigned int r = (x + 0x7fffu + ((x >> 16) & 1u)) >> 16;
    return (short)r;
}
static __device__ __forceinline__ void gload16(const void* g, void* l) {
    __builtin_amdgcn_global_load_lds((const __attribute__((address_space(1))) void*)g,
                                     (__attribute__((address_space(3))) void*)l, 16, 0, 0);
}

// ---------------- f32 -> bf16 row-major convert ----------------
__global__ __launch_bounds__(256)
void conv_x(const float* __restrict__ in, short* __restrict__ out, int n8) {
    for (int i = blockIdx.x * blockDim.x + threadIdx.x; i < n8;
         i += gridDim.x * blockDim.x) {
        float4 a = ((const float4*)in)[(size_t)i * 2];
        float4 b = ((const float4*)in)[(size_t)i * 2 + 1];
        bf16x8 o;
        o[0] = f2bf(a.x); o[1] = f2bf(a.y); o[2] = f2bf(a.z); o[3] = f2bf(a.w);
        o[4] = f2bf(b.x); o[5] = f2bf(b.y); o[6] = f2bf(b.z); o[7] = f2bf(b.w);
        ((bf16x8*)out)[i] = o;
    }
}

// ---------------- transpose-convert: W[R][C] f32 -> Wt[C][R] bf16 ----------------
__global__ __launch_bounds__(256)
void tkern(const float* __restrict__ W, short* __restrict__ Wt, int R, int C) {
    __shared__ short Ts[64 * 72];
    const int tid = threadIdx.x;
    const int r0 = blockIdx.y * 64, c0 = blockIdx.x * 64;
    for (int it = 0; it < 4; ++it) {
        int idx = it * 256 + tid;
        int row = idx >> 4, col4 = (idx & 15) * 4;
        float4 t = *(const float4*)&W[(size_t)(r0 + row) * C + c0 + col4];
        Ts[(col4 + 0) * 72 + row] = f2bf(t.x);
        Ts[(col4 + 1) * 72 + row] = f2bf(t.y);
        Ts[(col4 + 2) * 72 + row] = f2bf(t.z);
        Ts[(col4 + 3) * 72 + row] = f2bf(t.w);
    }
    __syncthreads();
    for (int it = 0; it < 2; ++it) {
        int idx = it * 256 + tid;
        int n = idx >> 3, k8 = (idx & 7) * 8;
        bf16x8 o = *(const bf16x8*)&Ts[n * 72 + k8];
        *(bf16x8*)&Wt[(size_t)(c0 + n) * R + r0 + k8] = o;
    }
}

// ---------------- bf16 GEMM, m97 structure: C[M,N] = A[M,K] @ Bt[N,K]^T ----------------
template <bool C_F32>
__global__ __launch_bounds__(256)
void gemm_bt(const short* __restrict__ A, const short* __restrict__ B,
             void* __restrict__ Cp, int M, int N, int K) {
    __shared__ short As[128 * 64];
    __shared__ short Bs[128 * 64];
    const int tid = threadIdx.x, lane = tid & 63, w = tid >> 6;
    const int wr = w >> 1, wc = w & 1, lr = lane & 15, lg = lane >> 4;
    const int m0 = blockIdx.y * 128, n0 = blockIdx.x * 128;
    const int l8 = lane >> 3, l7 = lane & 7;
    f32x4 acc[4][4] = {};

    for (int k0 = 0; k0 < K; k0 += 64) {
        __syncthreads();
        for (int it = 0; it < 4; ++it) {
            int row = w * 32 + it * 8 + l8;
            gload16(&A[(size_t)(m0 + row) * K + k0 + l7 * 8], &As[(w * 32 + it * 8) * 64]);
            gload16(&B[(size_t)(n0 + row) * K + k0 + l7 * 8], &Bs[(w * 32 + it * 8) * 64]);
        }
        __syncthreads();
        for (int kc = 0; kc < 2; ++kc) {
            bf16x8 af[4], bfr[4];
            for (int rb = 0; rb < 4; ++rb)
                af[rb] = *(const bf16x8*)&As[(wr * 64 + rb * 16 + lr) * 64 + kc * 32 + lg * 8];
            for (int cb = 0; cb < 4; ++cb)
                bfr[cb] = *(const bf16x8*)&Bs[(wc * 64 + cb * 16 + lr) * 64 + kc * 32 + lg * 8];
            __builtin_amdgcn_s_setprio(1);
            for (int rb = 0; rb < 4; ++rb)
                for (int cb = 0; cb < 4; ++cb)
                    acc[rb][cb] = __builtin_amdgcn_mfma_f32_16x16x32_bf16(
                        af[rb], bfr[cb], acc[rb][cb], 0, 0, 0);
            __builtin_amdgcn_s_setprio(0);
        }
    }

    for (int rb = 0; rb < 4; ++rb)
        for (int cb = 0; cb < 4; ++cb)
            for (int j = 0; j < 4; ++j) {
                int row = m0 + wr * 64 + rb * 16 + lg * 4 + j;
                int col = n0 + wc * 64 + cb * 16 + lr;
                float v = acc[rb][cb][j];
                if (C_F32) ((float*)Cp)[(size_t)row * N + col] = v;
                else ((short*)Cp)[(size_t)row * N + col] = f2bf(v);
            }
}

// ---------------- fallback GEMM (round-1): f32 inputs, convert in-kernel ----------------
template <bool A_F32, bool C_F32>
__global__ __launch_bounds__(256)
void gemm_kernel(const void* __restrict__ Ap, const float* __restrict__ Bp,
                 void* __restrict__ Cp, int M, int N, int K) {
    const int BK = 32, PAD = 8, LDT = BK + PAD;
    __shared__ short As[128 * LDT];
    __shared__ short Bt[128 * LDT];
    const int tid = threadIdx.x;
    const int lane = tid & 63, w = tid >> 6;
    const int wr = w >> 1, wc = w & 1;
    const int lr = lane & 15, lg = lane >> 4;
    const int m0 = blockIdx.y * 128, n0 = blockIdx.x * 128;
    f32x4 acc[4][4] = {};

    for (int k0 = 0; k0 < K; k0 += BK) {
        __syncthreads();
        for (int it = 0; it < 4; ++it) {
            int row = (tid >> 3) + it * 32;
            int kk = (tid & 7) * 4;
            short4 o;
            if (A_F32) {
                const float* A = (const float*)Ap;
                float4 t = *(const float4*)&A[(size_t)(m0 + row) * K + k0 + kk];
                o.x = f2bf(t.x); o.y = f2bf(t.y); o.z = f2bf(t.z); o.w = f2bf(t.w);
            } else {
                const short* A = (const short*)Ap;
                o = *(const short4*)&A[(size_t)(m0 + row) * K + k0 + kk];
            }
            *(short4*)&As[row * LDT + kk] = o;
        }
        for (int it = 0; it < 4; ++it) {
            int krow = (tid >> 5) + it * 8;
            int col = (tid & 31) * 4;
            float4 t = *(const float4*)&Bp[(size_t)(k0 + krow) * N + n0 + col];
            Bt[(col + 0) * LDT + krow] = f2bf(t.x);
            Bt[(col + 1) * LDT + krow] = f2bf(t.y);
            Bt[(col + 2) * LDT + krow] = f2bf(t.z);
            Bt[(col + 3) * LDT + krow] = f2bf(t.w);
        }
        __syncthreads();
        bf16x8 af[4], bfr[4];
        for (int rb = 0; rb < 4; ++rb)
            af[rb] = *(const bf16x8*)&As[(wr * 64 + rb * 16 + lr) * LDT + lg * 8];
        for (int cb = 0; cb < 4; ++cb)
            bfr[cb] = *(const bf16x8*)&Bt[(wc * 64 + cb * 16 + lr) * LDT + lg * 8];
        for (int rb = 0; rb < 4; ++rb)
            for (int cb = 0; cb < 4; ++cb)
                acc[rb][cb] = __builtin_amdgcn_mfma_f32_16x16x32_bf16(
                    af[rb], bfr[cb], acc[rb][cb], 0, 0, 0);
    }

    for (int rb = 0; rb < 4; ++rb)
        for (int cb = 0; cb < 4; ++cb)
            for (int j = 0; j < 4; ++j) {
                int row = m0 + wr * 64 + rb * 16 + lg * 4 + j;
                int col = n0 + wc * 64 + cb * 16 + lr;
                float v = acc[rb][cb][j];
                if (C_F32) ((float*)Cp)[(size_t)row * N + col] = v;
                else ((short*)Cp)[(size_t)row * N + col] = f2bf(v);
            }
}

// ---------------- RoPE in-place on bf16 Q and K ----------------
__global__ __launch_bounds__(256)
void rope_kernel(short* __restrict__ Qp, int ldq, short* __restrict__ Kp, int ldk) {
    const int QP = BATCH * SEQ * NHEADS * 64;
    const int KP = BATCH * SEQ * NKV * 64;
    const int total = QP + KP;
    for (int idx = blockIdx.x * blockDim.x + threadIdx.x; idx < total;
         idx += gridDim.x * blockDim.x) {
        short* base;
        size_t off;
        int i, row;
        if (idx < QP) {
            i = idx & 63;
            int hh = (idx >> 6) & (NHEADS - 1);
            row = idx >> 10;
            base = Qp;
            off = (size_t)row * ldq + hh * HD;
        } else {
            int t = idx - QP;
            i = t & 63;
            int hh = (t >> 6) & (NKV - 1);
            row = t >> 8;
            base = Kp;
            off = (size_t)row * ldk + hh * HD;
        }
        int pos = row & (SEQ - 1);
        float invf = exp2f(-(float)i * (13.287712379549449f / 64.0f));
        float ang = (float)pos * invf;
        float s, c;
        sincosf(ang, &s, &c);
        float t1 = bf2f(base[off + i]);
        float t2 = bf2f(base[off + i + 64]);
        base[off + i] = f2bf(t1 * c - t2 * s);
        base[off + i + 64] = f2bf(t2 * c + t1 * s);
    }
}

// ---------------- Flash attention: QBLK=128, paired q-tiles, swapped QK ----------------
// Block = 4 waves; wave w owns q-rows [q0+w*32, +32) as 2 groups of 16 (g=0,1).
// Each block processes q-tile qt=blockIdx.x then 15-blockIdx.x -> 34 KV-tiles total.
__global__ __launch_bounds__(256)
void attn_kernel(const short* __restrict__ Qp, int ldq,
                 const short* __restrict__ Kp, int ldk,
                 const short* __restrict__ Vp, int ldv,
                 short* __restrict__ O) {
    __shared__ short Ks[2][64 * 128];
    __shared__ short Vt[2][128 * 64];
    __shared__ short Pw[4][2][16 * 64];

    const int tid = threadIdx.x, lane = tid & 63, w = tid >> 6;
    const int lr = lane & 15, lg = lane >> 4;
    const int h = blockIdx.y, b = blockIdx.z;
    const int kvh = h >> 2;
    const size_t brow = (size_t)b * SEQ;
    const float scale = 0.08838834764831845f;  // 1/sqrt(128)

    const int d0 = lr * 8;
    const int rvb = (tid >> 4) * 2;
    bf16x8 vreg[2][2];

#define STAGE_K(T, BUF)                                                              \
    {                                                                                \
        _Pragma("unroll") for (int it = 0; it < 4; ++it) {                           \
            int row = w * 16 + it * 4 + (lane >> 4);                                 \
            int cblk = (lane & 15) ^ (row & 7);                                      \
            gload16(&Kp[(brow + (size_t)(T) * 64 + row) * ldk + kvh * HD + cblk * 8],\
                    &Ks[BUF][(w * 16 + it * 4) * 128]);                              \
        }                                                                            \
    }
#define LOAD_V(T)                                                                    \
    {                                                                                \
        _Pragma("unroll") for (int it = 0; it < 2; ++it)                             \
            _Pragma("unroll") for (int h2 = 0; h2 < 2; ++h2)                         \
                vreg[it][h2] = *(const bf16x8*)&Vp[(brow + (size_t)(T) * 64 + rvb +  \
                                                    it * 32 + h2) * ldv + kvh * HD + d0];\
    }
#define WRITE_V(BUF)                                                                 \
    {                                                                                \
        _Pragma("unroll") for (int it = 0; it < 2; ++it) {                           \
            int rv0 = rvb + it * 32;                                                 \
            _Pragma("unroll") for (int e = 0; e < 8; ++e) {                          \
                int d = d0 + e;                                                      \
                int g = (e ^ lr) & 7;                                                \
                unsigned int pk = ((unsigned int)(unsigned short)vreg[it][0][e]) |   \
                                  (((unsigned int)(unsigned short)vreg[it][1][e]) << 16);\
                *(unsigned int*)&Vt[BUF][d * 64 + (((rv0 >> 3) ^ g) << 3) + (rv0 & 7)] = pk;\
            }                                                                        \
        }                                                                            \
    }

    for (int pass = 0; pass < 2; ++pass) {
        const int qt = (pass == 0) ? (int)blockIdx.x : 15 - (int)blockIdx.x;
        const int q0 = qt * 128;
        const int qrow_g[2] = {q0 + w * 32 + lr, q0 + w * 32 + 16 + lr};

        // Q fragments, pre-scaled
        bf16x8 qf[2][4];
#pragma unroll
        for (int g = 0; g < 2; ++g)
#pragma unroll
            for (int kc = 0; kc < 4; ++kc) {
                bf16x8 r = *(const bf16x8*)&Qp[(brow + qrow_g[g]) * ldq + h * HD +
                                               kc * 32 + lg * 8];
#pragma unroll
                for (int e = 0; e < 8; ++e) r[e] = f2bf(bf2f(r[e]) * scale);
                qf[g][kc] = r;
            }

        f32x4 oacc[2][8] = {};
        float mrun[2] = {-__builtin_inff(), -__builtin_inff()};
        float lrun[2] = {0.f, 0.f};

        const int ntiles = 2 * qt + 2;

        STAGE_K(0, 0);
        LOAD_V(0);
        WRITE_V(0);
        __syncthreads();

        int cur = 0;
        for (int t = 0; t < ntiles; ++t) {
            const int kv0 = t * 64;
            const int nxt = cur ^ 1;
            const bool pre = (t + 1 < ntiles);
            if (pre) {
                if (nxt) { STAGE_K(t + 1, 1); } else { STAGE_K(t + 1, 0); }
                LOAD_V(t + 1);
            }

#pragma unroll
            for (int g = 0; g < 2; ++g) {
                const int qrow = qrow_g[g];
                // QK^T swapped: sacc[cb][j] = S^T[k=kv0+cb*16+lg*4+j][q=lr]
                f32x4 sacc[4] = {};
                __builtin_amdgcn_s_setprio(1);
#pragma unroll
                for (int cb = 0; cb < 4; ++cb)
#pragma unroll
                    for (int kc = 0; kc < 4; ++kc) {
                        bf16x8 kf = *(const bf16x8*)&Ks[cur][(cb * 16 + lr) * 128 +
                                                             (((kc * 4 + lg) ^ (lr & 7)) << 3)];
                        sacc[cb] = __builtin_amdgcn_mfma_f32_16x16x32_bf16(
                            kf, qf[g][kc], sacc[cb], 0, 0, 0);
                    }
                __builtin_amdgcn_s_setprio(0);

                float st[16];
                const bool need_mask = (kv0 + 63 > qrow);
#pragma unroll
                for (int cb = 0; cb < 4; ++cb)
#pragma unroll
                    for (int j = 0; j < 4; ++j) {
                        float s = sacc[cb][j];
                        if (need_mask) {
                            int col = kv0 + cb * 16 + lg * 4 + j;
                            if (col > qrow) s = -__builtin_inff();
                        }
                        st[cb * 4 + j] = s;
                    }
                float m8[8], m4[4];
#pragma unroll
                for (int i = 0; i < 8; ++i) m8[i] = fmaxf(st[i], st[i + 8]);
#pragma unroll
                for (int i = 0; i < 4; ++i) m4[i] = fmaxf(m8[i], m8[i + 4]);
                float rowmax = fmaxf(fmaxf(m4[0], m4[1]), fmaxf(m4[2], m4[3]));
                rowmax = fmaxf(rowmax, __shfl_xor(rowmax, 16, 64));
                rowmax = fmaxf(rowmax, __shfl_xor(rowmax, 32, 64));

                // defer-max (T13): skip rescale when growth <= 8
                if (!__all(rowmax <= mrun[g] + 8.f)) {
                    float mnew = fmaxf(mrun[g], rowmax);
                    float alpha = __expf(mrun[g] - mnew);
                    lrun[g] *= alpha;
#pragma unroll
                    for (int db = 0; db < 8; ++db) {
                        f32x4 o = oacc[g][db];
#pragma unroll
                        for (int j = 0; j < 4; ++j) o[j] *= alpha;
                        oacc[g][db] = o;
                    }
                    mrun[g] = mnew;
                }
                const float mbase = mrun[g];
#pragma unroll
                for (int i = 0; i < 16; ++i) st[i] = __expf(st[i] - mbase);
                float s8[8], s4[4];
#pragma unroll
                for (int i = 0; i < 8; ++i) s8[i] = st[i] + st[i + 8];
#pragma unroll
                for (int i = 0; i < 4; ++i) s4[i] = s8[i] + s8[i + 4];
                float rs = (s4[0] + s4[1]) + (s4[2] + s4[3]);
                rs += __shfl_xor(rs, 16, 64);
                rs += __shfl_xor(rs, 32, 64);
                lrun[g] += rs;

                // P^T -> per-wave-per-group LDS, 4x b64
#pragma unroll
                for (int cb = 0; cb < 4; ++cb) {
                    unsigned long long pk = 0;
#pragma unroll
                    for (int j = 0; j < 4; ++j)
                        pk |= ((unsigned long long)(unsigned short)f2bf(st[cb * 4 + j]))
                              << (16 * j);
                    int chunk = (cb * 2 + (lg >> 1)) ^ (lr & 7);
                    *(unsigned long long*)&Pw[w][g][lr * 64 + (chunk << 3) + (lg & 1) * 4] = pk;
                }
                bf16x8 pf[2];
#pragma unroll
                for (int kc = 0; kc < 2; ++kc)
                    pf[kc] = *(const bf16x8*)&Pw[w][g][lr * 64 +
                                                      (((kc * 4 + lg) ^ (lr & 7)) << 3)];

                // PV: oacc[g] accumulates O^T[d][q=lr]
                __builtin_amdgcn_s_setprio(1);
#pragma unroll
                for (int db = 0; db < 8; ++db)
#pragma unroll
                    for (int kc = 0; kc < 2; ++kc) {
                        int d = db * 16 + lr;
                        int gg = ((lr & 7) ^ (db * 2 + (lr >> 3))) & 7;
                        bf16x8 vf = *(const bf16x8*)&Vt[cur][d * 64 + (((kc * 4 + lg) ^ gg) << 3)];
                        oacc[g][db] = __builtin_amdgcn_mfma_f32_16x16x32_bf16(
                            vf, pf[kc], oacc[g][db], 0, 0, 0);
                    }
                __builtin_amdgcn_s_setprio(0);
            }

            if (pre) { if (nxt) { WRITE_V(1); } else { WRITE_V(0); } }
            __syncthreads();
            cur = nxt;
        }

        // epilogue: O[qrow_g][d], d = db*16+lg*4+j
#pragma unroll
        for (int g = 0; g < 2; ++g) {
            const float invl = 1.0f / lrun[g];
#pragma unroll
            for (int db = 0; db < 8; ++db) {
                short4 o4;
                o4.x = f2bf(oacc[g][db][0] * invl);
                o4.y = f2bf(oacc[g][db][1] * invl);
                o4.z = f2bf(oacc[g][db][2] * invl);
                o4.w = f2bf(oacc[g][db][3] * invl);
                *(short4*)&O[(brow + qrow_g[g]) * DMODEL + h * HD + db * 16 + lg * 4] = o4;
            }
        }
    }
#undef STAGE_K
#undef LOAD_V
#undef WRITE_V
}

extern "C" void kernel_launch(void* const* d_in, const int* in_sizes, int n_in,
                              void* d_out, int out_size, void* d_ws, size_t ws_size,
                              hipStream_t stream) {
    const float* x = (const float*)d_in[0];
    const float* Wq = (const float*)d_in[1];
    const float* Wk = (const float*)d_in[2];
    const float* Wv = (const float*)d_in[3];
    const float* Wo = (const float*)d_in[4];
    float* out = (float*)d_out;

    const size_t BS = (size_t)BATCH * SEQ;  // 8192
    dim3 blk(256);

    const size_t planA_shorts = BS * 2048 + BS * 3072 + (size_t)3072 * 2048 + (size_t)2048 * 2048;
    if (ws_size >= planA_shorts * 2) {
        short* xb = (short*)d_ws;                    // [8192][2048] bf16 (reused as AO)
        short* QKV = xb + BS * 2048;                 // [8192][3072]: Q | K | V
        short* WqkvT = QKV + BS * 3072;              // [3072][2048]
        short* WoT = WqkvT + (size_t)3072 * 2048;    // [2048][2048]
        short* AO = xb;

        conv_x<<<dim3(2048), blk, 0, stream>>>(x, xb, (int)(BS * 2048 / 8));
        tkern<<<dim3(32, 32), blk, 0, stream>>>(Wq, WqkvT, 2048, 2048);
        tkern<<<dim3(8, 32), blk, 0, stream>>>(Wk, WqkvT + (size_t)2048 * 2048, 2048, 512);
        tkern<<<dim3(8, 32), blk, 0, stream>>>(Wv, WqkvT + (size_t)2560 * 2048, 2048, 512);
        tkern<<<dim3(32, 32), blk, 0, stream>>>(Wo, WoT, 2048, 2048);
        gemm_bt<false><<<dim3(24, 64), blk, 0, stream>>>(xb, WqkvT, (void*)QKV, 8192, 3072, 2048);
        rope_kernel<<<dim3(4096), blk, 0, stream>>>(QKV, 3072, QKV + 2048, 3072);
        attn_kernel<<<dim3(8, NHEADS, BATCH), blk, 0, stream>>>(
            QKV, 3072, QKV + 2048, 3072, QKV + 2560, 3072, AO);
        gemm_bt<true><<<dim3(16, 64), blk, 0, stream>>>(AO, WoT, (void*)out, 8192, 2048, 2048);
    } else {
        short* Qb = (short*)d_ws;
        short* Kb = Qb + BS * DMODEL;
        short* Vb = Kb + BS * (NKV * HD);
        short* AO = Vb + BS * (NKV * HD);
        gemm_kernel<true, false><<<dim3(16, 64), blk, 0, stream>>>((const void*)x, Wq, (void*)Qb, 8192, 2048, 2048);
        gemm_kernel<true, false><<<dim3(4, 64), blk, 0, stream>>>((const void*)x, Wk, (void*)Kb, 8192, 512, 2048);
        gemm_kernel<true, false><<<dim3(4, 64), blk, 0, stream>>>((const void*)x, Wv, (void*)Vb, 8192, 512, 2048);
        rope_kernel<<<dim3(4096), blk, 0, stream>>>(Qb, 2048, Kb, 512);
        attn_kernel<<<dim3(8, NHEADS, BATCH), blk, 0, stream>>>(
            Qb, 2048, Kb, 512, Vb, 512, AO);
        gemm_kernel<false, true><<<dim3(16, 64), blk, 0, stream>>>((const void*)AO, Wo, (void*)out, 8192, 2048, 2048);
    }
}

// Round 5
// 514.650 us; speedup vs baseline: 3.1769x; 1.0088x over previous
//
#include <hip/hip_runtime.h>
#include <hip/hip_bf16.h>

#define DMODEL 2048
#define NHEADS 16
#define NKV 4
#define HD 128
#define SEQ 2048
#define BATCH 4

typedef __attribute__((ext_vector_type(4))) float f32x4;
typedef __attribute__((ext_vector_type(8))) short bf16x8;

static __device__ __forceinline__ float bf2f(short u) {
    unsigned int x = ((unsigned int)(unsigned short)u) << 16;
    return __builtin_bit_cast(float, x);
}
static __device__ __forceinline__ short f2bf(float f) {
    unsigned int x = __builtin_bit_cast(unsigned int, f);
    unsigned int r = (x + 0x7fffu + ((x >> 16) & 1u)) >> 16;
    return (short)r;
}
static __device__ __forceinline__ void gload16(const void* g, void* l) {
    __builtin_amdgcn_global_load_lds((const __attribute__((address_space(1))) void*)g,
                                     (__attribute__((address_space(3))) void*)l, 16, 0, 0);
}

// ---------------- f32 -> bf16 row-major convert ----------------
__global__ __launch_bounds__(256)
void conv_x(const float* __restrict__ in, short* __restrict__ out, int n8) {
    for (int i = blockIdx.x * blockDim.x + threadIdx.x; i < n8;
         i += gridDim.x * blockDim.x) {
        float4 a = ((const float4*)in)[(size_t)i * 2];
        float4 b = ((const float4*)in)[(size_t)i * 2 + 1];
        bf16x8 o;
        o[0] = f2bf(a.x); o[1] = f2bf(a.y); o[2] = f2bf(a.z); o[3] = f2bf(a.w);
        o[4] = f2bf(b.x); o[5] = f2bf(b.y); o[6] = f2bf(b.z); o[7] = f2bf(b.w);
        ((bf16x8*)out)[i] = o;
    }
}

// ---------------- transpose-convert: W[R][C] f32 -> Wt[C][R] bf16 ----------------
__global__ __launch_bounds__(256)
void tkern(const float* __restrict__ W, short* __restrict__ Wt, int R, int C) {
    __shared__ short Ts[64 * 72];
    const int tid = threadIdx.x;
    const int r0 = blockIdx.y * 64, c0 = blockIdx.x * 64;
    for (int it = 0; it < 4; ++it) {
        int idx = it * 256 + tid;
        int row = idx >> 4, col4 = (idx & 15) * 4;
        float4 t = *(const float4*)&W[(size_t)(r0 + row) * C + c0 + col4];
        Ts[(col4 + 0) * 72 + row] = f2bf(t.x);
        Ts[(col4 + 1) * 72 + row] = f2bf(t.y);
        Ts[(col4 + 2) * 72 + row] = f2bf(t.z);
        Ts[(col4 + 3) * 72 + row] = f2bf(t.w);
    }
    __syncthreads();
    for (int it = 0; it < 2; ++it) {
        int idx = it * 256 + tid;
        int n = idx >> 3, k8 = (idx & 7) * 8;
        bf16x8 o = *(const bf16x8*)&Ts[n * 72 + k8];
        *(bf16x8*)&Wt[(size_t)(c0 + n) * R + r0 + k8] = o;
    }
}

// ---------------- bf16 GEMM, m97 structure: C[M,N] = A[M,K] @ Bt[N,K]^T ----------------
template <bool C_F32>
__global__ __launch_bounds__(256)
void gemm_bt(const short* __restrict__ A, const short* __restrict__ B,
             void* __restrict__ Cp, int M, int N, int K) {
    __shared__ short As[128 * 64];
    __shared__ short Bs[128 * 64];
    const int tid = threadIdx.x, lane = tid & 63, w = tid >> 6;
    const int wr = w >> 1, wc = w & 1, lr = lane & 15, lg = lane >> 4;
    const int m0 = blockIdx.y * 128, n0 = blockIdx.x * 128;
    const int l8 = lane >> 3, l7 = lane & 7;
    f32x4 acc[4][4] = {};

    for (int k0 = 0; k0 < K; k0 += 64) {
        __syncthreads();
        for (int it = 0; it < 4; ++it) {
            int row = w * 32 + it * 8 + l8;
            gload16(&A[(size_t)(m0 + row) * K + k0 + l7 * 8], &As[(w * 32 + it * 8) * 64]);
            gload16(&B[(size_t)(n0 + row) * K + k0 + l7 * 8], &Bs[(w * 32 + it * 8) * 64]);
        }
        __syncthreads();
        for (int kc = 0; kc < 2; ++kc) {
            bf16x8 af[4], bfr[4];
            for (int rb = 0; rb < 4; ++rb)
                af[rb] = *(const bf16x8*)&As[(wr * 64 + rb * 16 + lr) * 64 + kc * 32 + lg * 8];
            for (int cb = 0; cb < 4; ++cb)
                bfr[cb] = *(const bf16x8*)&Bs[(wc * 64 + cb * 16 + lr) * 64 + kc * 32 + lg * 8];
            __builtin_amdgcn_s_setprio(1);
            for (int rb = 0; rb < 4; ++rb)
                for (int cb = 0; cb < 4; ++cb)
                    acc[rb][cb] = __builtin_amdgcn_mfma_f32_16x16x32_bf16(
                        af[rb], bfr[cb], acc[rb][cb], 0, 0, 0);
            __builtin_amdgcn_s_setprio(0);
        }
    }

    for (int rb = 0; rb < 4; ++rb)
        for (int cb = 0; cb < 4; ++cb)
            for (int j = 0; j < 4; ++j) {
                int row = m0 + wr * 64 + rb * 16 + lg * 4 + j;
                int col = n0 + wc * 64 + cb * 16 + lr;
                float v = acc[rb][cb][j];
                if (C_F32) ((float*)Cp)[(size_t)row * N + col] = v;
                else ((short*)Cp)[(size_t)row * N + col] = f2bf(v);
            }
}

// ---------------- fallback GEMM (round-1): f32 inputs, convert in-kernel ----------------
template <bool A_F32, bool C_F32>
__global__ __launch_bounds__(256)
void gemm_kernel(const void* __restrict__ Ap, const float* __restrict__ Bp,
                 void* __restrict__ Cp, int M, int N, int K) {
    const int BK = 32, PAD = 8, LDT = BK + PAD;
    __shared__ short As[128 * LDT];
    __shared__ short Bt[128 * LDT];
    const int tid = threadIdx.x;
    const int lane = tid & 63, w = tid >> 6;
    const int wr = w >> 1, wc = w & 1;
    const int lr = lane & 15, lg = lane >> 4;
    const int m0 = blockIdx.y * 128, n0 = blockIdx.x * 128;
    f32x4 acc[4][4] = {};

    for (int k0 = 0; k0 < K; k0 += BK) {
        __syncthreads();
        for (int it = 0; it < 4; ++it) {
            int row = (tid >> 3) + it * 32;
            int kk = (tid & 7) * 4;
            short4 o;
            if (A_F32) {
                const float* A = (const float*)Ap;
                float4 t = *(const float4*)&A[(size_t)(m0 + row) * K + k0 + kk];
                o.x = f2bf(t.x); o.y = f2bf(t.y); o.z = f2bf(t.z); o.w = f2bf(t.w);
            } else {
                const short* A = (const short*)Ap;
                o = *(const short4*)&A[(size_t)(m0 + row) * K + k0 + kk];
            }
            *(short4*)&As[row * LDT + kk] = o;
        }
        for (int it = 0; it < 4; ++it) {
            int krow = (tid >> 5) + it * 8;
            int col = (tid & 31) * 4;
            float4 t = *(const float4*)&Bp[(size_t)(k0 + krow) * N + n0 + col];
            Bt[(col + 0) * LDT + krow] = f2bf(t.x);
            Bt[(col + 1) * LDT + krow] = f2bf(t.y);
            Bt[(col + 2) * LDT + krow] = f2bf(t.z);
            Bt[(col + 3) * LDT + krow] = f2bf(t.w);
        }
        __syncthreads();
        bf16x8 af[4], bfr[4];
        for (int rb = 0; rb < 4; ++rb)
            af[rb] = *(const bf16x8*)&As[(wr * 64 + rb * 16 + lr) * LDT + lg * 8];
        for (int cb = 0; cb < 4; ++cb)
            bfr[cb] = *(const bf16x8*)&Bt[(wc * 64 + cb * 16 + lr) * LDT + lg * 8];
        for (int rb = 0; rb < 4; ++rb)
            for (int cb = 0; cb < 4; ++cb)
                acc[rb][cb] = __builtin_amdgcn_mfma_f32_16x16x32_bf16(
                    af[rb], bfr[cb], acc[rb][cb], 0, 0, 0);
    }

    for (int rb = 0; rb < 4; ++rb)
        for (int cb = 0; cb < 4; ++cb)
            for (int j = 0; j < 4; ++j) {
                int row = m0 + wr * 64 + rb * 16 + lg * 4 + j;
                int col = n0 + wc * 64 + cb * 16 + lr;
                float v = acc[rb][cb][j];
                if (C_F32) ((float*)Cp)[(size_t)row * N + col] = v;
                else ((short*)Cp)[(size_t)row * N + col] = f2bf(v);
            }
}

// ---------------- RoPE in-place on bf16 Q and K ----------------
__global__ __launch_bounds__(256)
void rope_kernel(short* __restrict__ Qp, int ldq, short* __restrict__ Kp, int ldk) {
    const int QP = BATCH * SEQ * NHEADS * 64;
    const int KP = BATCH * SEQ * NKV * 64;
    const int total = QP + KP;
    for (int idx = blockIdx.x * blockDim.x + threadIdx.x; idx < total;
         idx += gridDim.x * blockDim.x) {
        short* base;
        size_t off;
        int i, row;
        if (idx < QP) {
            i = idx & 63;
            int hh = (idx >> 6) & (NHEADS - 1);
            row = idx >> 10;
            base = Qp;
            off = (size_t)row * ldq + hh * HD;
        } else {
            int t = idx - QP;
            i = t & 63;
            int hh = (t >> 6) & (NKV - 1);
            row = t >> 8;
            base = Kp;
            off = (size_t)row * ldk + hh * HD;
        }
        int pos = row & (SEQ - 1);
        float invf = exp2f(-(float)i * (13.287712379549449f / 64.0f));
        float ang = (float)pos * invf;
        float s, c;
        sincosf(ang, &s, &c);
        float t1 = bf2f(base[off + i]);
        float t2 = bf2f(base[off + i + 64]);
        base[off + i] = f2bf(t1 * c - t2 * s);
        base[off + i + 64] = f2bf(t2 * c + t1 * s);
    }
}

// ---------------- Flash attention: QBLK=128, paired q-tiles, 56KB LDS ----------------
// Block = 4 waves; wave w owns q-rows [q0+w*32, +32) as 2 groups of 16 (g=0,1).
// LDS: Ks dbuf 32K + Vt single 16K + Pw shared-across-g 8K = 56K -> 2 blocks/CU.
// Tile: {STAGE_K(t+1,nxt), LOAD_V(t+1)} -> compute (QK/softmax/PV) -> bar ->
//       WRITE_V(t+1) -> bar.
__global__ __launch_bounds__(256)
void attn_kernel(const short* __restrict__ Qp, int ldq,
                 const short* __restrict__ Kp, int ldk,
                 const short* __restrict__ Vp, int ldv,
                 short* __restrict__ O) {
    __shared__ short Ks[2][64 * 128];
    __shared__ short Vt[128 * 64];
    __shared__ short Pw[4][16 * 64];

    const int tid = threadIdx.x, lane = tid & 63, w = tid >> 6;
    const int lr = lane & 15, lg = lane >> 4;
    const int h = blockIdx.y, b = blockIdx.z;
    const int kvh = h >> 2;
    const size_t brow = (size_t)b * SEQ;
    const float scale = 0.08838834764831845f;  // 1/sqrt(128)

    const int d0 = lr * 8;
    const int rvb = (tid >> 4) * 2;
    bf16x8 vreg[2][2];

#define STAGE_K(T, BUF)                                                              \
    {                                                                                \
        _Pragma("unroll") for (int it = 0; it < 4; ++it) {                           \
            int row = w * 16 + it * 4 + (lane >> 4);                                 \
            int cblk = (lane & 15) ^ (row & 7);                                      \
            gload16(&Kp[(brow + (size_t)(T) * 64 + row) * ldk + kvh * HD + cblk * 8],\
                    &Ks[BUF][(w * 16 + it * 4) * 128]);                              \
        }                                                                            \
    }
#define LOAD_V(T)                                                                    \
    {                                                                                \
        _Pragma("unroll") for (int it = 0; it < 2; ++it)                             \
            _Pragma("unroll") for (int h2 = 0; h2 < 2; ++h2)                         \
                vreg[it][h2] = *(const bf16x8*)&Vp[(brow + (size_t)(T) * 64 + rvb +  \
                                                    it * 32 + h2) * ldv + kvh * HD + d0];\
    }
#define WRITE_V()                                                                    \
    {                                                                                \
        _Pragma("unroll") for (int it = 0; it < 2; ++it) {                           \
            int rv0 = rvb + it * 32;                                                 \
            _Pragma("unroll") for (int e = 0; e < 8; ++e) {                          \
                int d = d0 + e;                                                      \
                int g = (e ^ lr) & 7;                                                \
                unsigned int pk = ((unsigned int)(unsigned short)vreg[it][0][e]) |   \
                                  (((unsigned int)(unsigned short)vreg[it][1][e]) << 16);\
                *(unsigned int*)&Vt[d * 64 + (((rv0 >> 3) ^ g) << 3) + (rv0 & 7)] = pk;\
            }                                                                        \
        }                                                                            \
    }

    for (int pass = 0; pass < 2; ++pass) {
        const int qt = (pass == 0) ? (int)blockIdx.x : 15 - (int)blockIdx.x;
        const int q0 = qt * 128;
        const int qrow_g[2] = {q0 + w * 32 + lr, q0 + w * 32 + 16 + lr};

        // Q fragments, pre-scaled
        bf16x8 qf[2][4];
#pragma unroll
        for (int g = 0; g < 2; ++g)
#pragma unroll
            for (int kc = 0; kc < 4; ++kc) {
                bf16x8 r = *(const bf16x8*)&Qp[(brow + qrow_g[g]) * ldq + h * HD +
                                               kc * 32 + lg * 8];
#pragma unroll
                for (int e = 0; e < 8; ++e) r[e] = f2bf(bf2f(r[e]) * scale);
                qf[g][kc] = r;
            }

        f32x4 oacc[2][8] = {};
        float mrun[2] = {-__builtin_inff(), -__builtin_inff()};
        float lrun[2] = {0.f, 0.f};

        const int ntiles = 2 * qt + 2;

        // prologue (barrier protects Vt against previous pass's readers)
        STAGE_K(0, 0);
        LOAD_V(0);
        __syncthreads();
        WRITE_V();
        __syncthreads();

        int cur = 0;
        for (int t = 0; t < ntiles; ++t) {
            const int kv0 = t * 64;
            const int nxt = cur ^ 1;
            const bool pre = (t + 1 < ntiles);
            if (pre) {
                if (nxt) { STAGE_K(t + 1, 1); } else { STAGE_K(t + 1, 0); }
                LOAD_V(t + 1);
            }

#pragma unroll
            for (int g = 0; g < 2; ++g) {
                const int qrow = qrow_g[g];
                // QK^T swapped: sacc[cb][j] = S^T[k=kv0+cb*16+lg*4+j][q=lr]
                f32x4 sacc[4] = {};
                __builtin_amdgcn_s_setprio(1);
#pragma unroll
                for (int cb = 0; cb < 4; ++cb)
#pragma unroll
                    for (int kc = 0; kc < 4; ++kc) {
                        bf16x8 kf = *(const bf16x8*)&Ks[cur][(cb * 16 + lr) * 128 +
                                                             (((kc * 4 + lg) ^ (lr & 7)) << 3)];
                        sacc[cb] = __builtin_amdgcn_mfma_f32_16x16x32_bf16(
                            kf, qf[g][kc], sacc[cb], 0, 0, 0);
                    }
                __builtin_amdgcn_s_setprio(0);

                float st[16];
                const bool need_mask = (kv0 + 63 > qrow);
#pragma unroll
                for (int cb = 0; cb < 4; ++cb)
#pragma unroll
                    for (int j = 0; j < 4; ++j) {
                        float s = sacc[cb][j];
                        if (need_mask) {
                            int col = kv0 + cb * 16 + lg * 4 + j;
                            if (col > qrow) s = -__builtin_inff();
                        }
                        st[cb * 4 + j] = s;
                    }
                float m8[8], m4[4];
#pragma unroll
                for (int i = 0; i < 8; ++i) m8[i] = fmaxf(st[i], st[i + 8]);
#pragma unroll
                for (int i = 0; i < 4; ++i) m4[i] = fmaxf(m8[i], m8[i + 4]);
                float rowmax = fmaxf(fmaxf(m4[0], m4[1]), fmaxf(m4[2], m4[3]));
                rowmax = fmaxf(rowmax, __shfl_xor(rowmax, 16, 64));
                rowmax = fmaxf(rowmax, __shfl_xor(rowmax, 32, 64));

                // defer-max (T13): skip rescale when growth <= 8
                if (!__all(rowmax <= mrun[g] + 8.f)) {
                    float mnew = fmaxf(mrun[g], rowmax);
                    float alpha = __expf(mrun[g] - mnew);
                    lrun[g] *= alpha;
#pragma unroll
                    for (int db = 0; db < 8; ++db) {
                        f32x4 o = oacc[g][db];
#pragma unroll
                        for (int j = 0; j < 4; ++j) o[j] *= alpha;
                        oacc[g][db] = o;
                    }
                    mrun[g] = mnew;
                }
                const float mbase = mrun[g];
#pragma unroll
                for (int i = 0; i < 16; ++i) st[i] = __expf(st[i] - mbase);
                float s8[8], s4[4];
#pragma unroll
                for (int i = 0; i < 8; ++i) s8[i] = st[i] + st[i + 8];
#pragma unroll
                for (int i = 0; i < 4; ++i) s4[i] = s8[i] + s8[i + 4];
                float rs = (s4[0] + s4[1]) + (s4[2] + s4[3]);
                rs += __shfl_xor(rs, 16, 64);
                rs += __shfl_xor(rs, 32, 64);
                lrun[g] += rs;

                // P^T -> per-wave LDS (shared across g; same-wave ordering by compiler)
#pragma unroll
                for (int cb = 0; cb < 4; ++cb) {
                    unsigned long long pk = 0;
#pragma unroll
                    for (int j = 0; j < 4; ++j)
                        pk |= ((unsigned long long)(unsigned short)f2bf(st[cb * 4 + j]))
                              << (16 * j);
                    int chunk = (cb * 2 + (lg >> 1)) ^ (lr & 7);
                    *(unsigned long long*)&Pw[w][lr * 64 + (chunk << 3) + (lg & 1) * 4] = pk;
                }
                bf16x8 pf[2];
#pragma unroll
                for (int kc = 0; kc < 2; ++kc)
                    pf[kc] = *(const bf16x8*)&Pw[w][lr * 64 +
                                                   (((kc * 4 + lg) ^ (lr & 7)) << 3)];

                // PV: oacc[g] accumulates O^T[d][q=lr]
                __builtin_amdgcn_s_setprio(1);
#pragma unroll
                for (int db = 0; db < 8; ++db)
#pragma unroll
                    for (int kc = 0; kc < 2; ++kc) {
                        int d = db * 16 + lr;
                        int gg = ((lr & 7) ^ (db * 2 + (lr >> 3))) & 7;
                        bf16x8 vf = *(const bf16x8*)&Vt[d * 64 + (((kc * 4 + lg) ^ gg) << 3)];
                        oacc[g][db] = __builtin_amdgcn_mfma_f32_16x16x32_bf16(
                            vf, pf[kc], oacc[g][db], 0, 0, 0);
                    }
                __builtin_amdgcn_s_setprio(0);
            }

            if (pre) {
                __syncthreads();   // all PV reads of Vt done; K(t+1) gloads drained
                WRITE_V();
                __syncthreads();   // Vt(t+1) + Ks[nxt] visible
                cur = nxt;
            }
        }

        // epilogue: O[qrow_g][d], d = db*16+lg*4+j
#pragma unroll
        for (int g = 0; g < 2; ++g) {
            const float invl = 1.0f / lrun[g];
#pragma unroll
            for (int db = 0; db < 8; ++db) {
                short4 o4;
                o4.x = f2bf(oacc[g][db][0] * invl);
                o4.y = f2bf(oacc[g][db][1] * invl);
                o4.z = f2bf(oacc[g][db][2] * invl);
                o4.w = f2bf(oacc[g][db][3] * invl);
                *(short4*)&O[(brow + qrow_g[g]) * DMODEL + h * HD + db * 16 + lg * 4] = o4;
            }
        }
    }
#undef STAGE_K
#undef LOAD_V
#undef WRITE_V
}

extern "C" void kernel_launch(void* const* d_in, const int* in_sizes, int n_in,
                              void* d_out, int out_size, void* d_ws, size_t ws_size,
                              hipStream_t stream) {
    const float* x = (const float*)d_in[0];
    const float* Wq = (const float*)d_in[1];
    const float* Wk = (const float*)d_in[2];
    const float* Wv = (const float*)d_in[3];
    const float* Wo = (const float*)d_in[4];
    float* out = (float*)d_out;

    const size_t BS = (size_t)BATCH * SEQ;  // 8192
    dim3 blk(256);

    const size_t planA_shorts = BS * 2048 + BS * 3072 + (size_t)3072 * 2048 + (size_t)2048 * 2048;
    if (ws_size >= planA_shorts * 2) {
        short* xb = (short*)d_ws;                    // [8192][2048] bf16 (reused as AO)
        short* QKV = xb + BS * 2048;                 // [8192][3072]: Q | K | V
        short* WqkvT = QKV + BS * 3072;              // [3072][2048]
        short* WoT = WqkvT + (size_t)3072 * 2048;    // [2048][2048]
        short* AO = xb;

        conv_x<<<dim3(2048), blk, 0, stream>>>(x, xb, (int)(BS * 2048 / 8));
        tkern<<<dim3(32, 32), blk, 0, stream>>>(Wq, WqkvT, 2048, 2048);
        tkern<<<dim3(8, 32), blk, 0, stream>>>(Wk, WqkvT + (size_t)2048 * 2048, 2048, 512);
        tkern<<<dim3(8, 32), blk, 0, stream>>>(Wv, WqkvT + (size_t)2560 * 2048, 2048, 512);
        tkern<<<dim3(32, 32), blk, 0, stream>>>(Wo, WoT, 2048, 2048);
        gemm_bt<false><<<dim3(24, 64), blk, 0, stream>>>(xb, WqkvT, (void*)QKV, 8192, 3072, 2048);
        rope_kernel<<<dim3(4096), blk, 0, stream>>>(QKV, 3072, QKV + 2048, 3072);
        attn_kernel<<<dim3(8, NHEADS, BATCH), blk, 0, stream>>>(
            QKV, 3072, QKV + 2048, 3072, QKV + 2560, 3072, AO);
        gemm_bt<true><<<dim3(16, 64), blk, 0, stream>>>(AO, WoT, (void*)out, 8192, 2048, 2048);
    } else {
        short* Qb = (short*)d_ws;
        short* Kb = Qb + BS * DMODEL;
        short* Vb = Kb + BS * (NKV * HD);
        short* AO = Vb + BS * (NKV * HD);
        gemm_kernel<true, false><<<dim3(16, 64), blk, 0, stream>>>((const void*)x, Wq, (void*)Qb, 8192, 2048, 2048);
        gemm_kernel<true, false><<<dim3(4, 64), blk, 0, stream>>>((const void*)x, Wk, (void*)Kb, 8192, 512, 2048);
        gemm_kernel<true, false><<<dim3(4, 64), blk, 0, stream>>>((const void*)x, Wv, (void*)Vb, 8192, 512, 2048);
        rope_kernel<<<dim3(4096), blk, 0, stream>>>(Qb, 2048, Kb, 512);
        attn_kernel<<<dim3(8, NHEADS, BATCH), blk, 0, stream>>>(
            Qb, 2048, Kb, 512, Vb, 512, AO);
        gemm_kernel<false, true><<<dim3(16, 64), blk, 0, stream>>>((const void*)AO, Wo, (void*)out, 8192, 2048, 2048);
    }
}

// Round 6
// 440.884 us; speedup vs baseline: 3.7084x; 1.1673x over previous
//
#include <hip/hip_runtime.h>
#include <hip/hip_bf16.h>

#define DMODEL 2048
#define NHEADS 16
#define NKV 4
#define HD 128
#define SEQ 2048
#define BATCH 4

typedef __attribute__((ext_vector_type(4))) float f32x4;
typedef __attribute__((ext_vector_type(8))) short bf16x8;

static __device__ __forceinline__ float bf2f(short u) {
    unsigned int x = ((unsigned int)(unsigned short)u) << 16;
    return __builtin_bit_cast(float, x);
}
static __device__ __forceinline__ short f2bf(float f) {
    unsigned int x = __builtin_bit_cast(unsigned int, f);
    unsigned int r = (x + 0x7fffu + ((x >> 16) & 1u)) >> 16;
    return (short)r;
}
static __device__ __forceinline__ unsigned int cvtpk_bf16(float lo, float hi) {
    unsigned int r;
    asm("v_cvt_pk_bf16_f32 %0, %1, %2" : "=v"(r) : "v"(lo), "v"(hi));
    return r;
}
static __device__ __forceinline__ void gload16(const void* g, void* l) {
    __builtin_amdgcn_global_load_lds((const __attribute__((address_space(1))) void*)g,
                                     (__attribute__((address_space(3))) void*)l, 16, 0, 0);
}

// ---------------- f32 -> bf16 row-major convert ----------------
__global__ __launch_bounds__(256)
void conv_x(const float* __restrict__ in, short* __restrict__ out, int n8) {
    for (int i = blockIdx.x * blockDim.x + threadIdx.x; i < n8;
         i += gridDim.x * blockDim.x) {
        float4 a = ((const float4*)in)[(size_t)i * 2];
        float4 b = ((const float4*)in)[(size_t)i * 2 + 1];
        bf16x8 o;
        o[0] = f2bf(a.x); o[1] = f2bf(a.y); o[2] = f2bf(a.z); o[3] = f2bf(a.w);
        o[4] = f2bf(b.x); o[5] = f2bf(b.y); o[6] = f2bf(b.z); o[7] = f2bf(b.w);
        ((bf16x8*)out)[i] = o;
    }
}

// ---------------- transpose-convert: W[R][C] f32 -> Wt[C][R] bf16 ----------------
__global__ __launch_bounds__(256)
void tkern(const float* __restrict__ W, short* __restrict__ Wt, int R, int C) {
    __shared__ short Ts[64 * 72];
    const int tid = threadIdx.x;
    const int r0 = blockIdx.y * 64, c0 = blockIdx.x * 64;
    for (int it = 0; it < 4; ++it) {
        int idx = it * 256 + tid;
        int row = idx >> 4, col4 = (idx & 15) * 4;
        float4 t = *(const float4*)&W[(size_t)(r0 + row) * C + c0 + col4];
        Ts[(col4 + 0) * 72 + row] = f2bf(t.x);
        Ts[(col4 + 1) * 72 + row] = f2bf(t.y);
        Ts[(col4 + 2) * 72 + row] = f2bf(t.z);
        Ts[(col4 + 3) * 72 + row] = f2bf(t.w);
    }
    __syncthreads();
    for (int it = 0; it < 2; ++it) {
        int idx = it * 256 + tid;
        int n = idx >> 3, k8 = (idx & 7) * 8;
        bf16x8 o = *(const bf16x8*)&Ts[n * 72 + k8];
        *(bf16x8*)&Wt[(size_t)(c0 + n) * R + r0 + k8] = o;
    }
}

// ---------------- bf16 GEMM, m97 structure: C[M,N] = A[M,K] @ Bt[N,K]^T ----------------
template <bool C_F32>
__global__ __launch_bounds__(256)
void gemm_bt(const short* __restrict__ A, const short* __restrict__ B,
             void* __restrict__ Cp, int M, int N, int K) {
    __shared__ short As[128 * 64];
    __shared__ short Bs[128 * 64];
    const int tid = threadIdx.x, lane = tid & 63, w = tid >> 6;
    const int wr = w >> 1, wc = w & 1, lr = lane & 15, lg = lane >> 4;
    const int m0 = blockIdx.y * 128, n0 = blockIdx.x * 128;
    const int l8 = lane >> 3, l7 = lane & 7;
    f32x4 acc[4][4] = {};

    for (int k0 = 0; k0 < K; k0 += 64) {
        __syncthreads();
        for (int it = 0; it < 4; ++it) {
            int row = w * 32 + it * 8 + l8;
            gload16(&A[(size_t)(m0 + row) * K + k0 + l7 * 8], &As[(w * 32 + it * 8) * 64]);
            gload16(&B[(size_t)(n0 + row) * K + k0 + l7 * 8], &Bs[(w * 32 + it * 8) * 64]);
        }
        __syncthreads();
        for (int kc = 0; kc < 2; ++kc) {
            bf16x8 af[4], bfr[4];
            for (int rb = 0; rb < 4; ++rb)
                af[rb] = *(const bf16x8*)&As[(wr * 64 + rb * 16 + lr) * 64 + kc * 32 + lg * 8];
            for (int cb = 0; cb < 4; ++cb)
                bfr[cb] = *(const bf16x8*)&Bs[(wc * 64 + cb * 16 + lr) * 64 + kc * 32 + lg * 8];
            __builtin_amdgcn_s_setprio(1);
            for (int rb = 0; rb < 4; ++rb)
                for (int cb = 0; cb < 4; ++cb)
                    acc[rb][cb] = __builtin_amdgcn_mfma_f32_16x16x32_bf16(
                        af[rb], bfr[cb], acc[rb][cb], 0, 0, 0);
            __builtin_amdgcn_s_setprio(0);
        }
    }

    for (int rb = 0; rb < 4; ++rb)
        for (int cb = 0; cb < 4; ++cb)
            for (int j = 0; j < 4; ++j) {
                int row = m0 + wr * 64 + rb * 16 + lg * 4 + j;
                int col = n0 + wc * 64 + cb * 16 + lr;
                float v = acc[rb][cb][j];
                if (C_F32) ((float*)Cp)[(size_t)row * N + col] = v;
                else ((short*)Cp)[(size_t)row * N + col] = f2bf(v);
            }
}

// ---------------- fallback GEMM (round-1): f32 inputs, convert in-kernel ----------------
template <bool A_F32, bool C_F32>
__global__ __launch_bounds__(256)
void gemm_kernel(const void* __restrict__ Ap, const float* __restrict__ Bp,
                 void* __restrict__ Cp, int M, int N, int K) {
    const int BK = 32, PAD = 8, LDT = BK + PAD;
    __shared__ short As[128 * LDT];
    __shared__ short Bt[128 * LDT];
    const int tid = threadIdx.x;
    const int lane = tid & 63, w = tid >> 6;
    const int wr = w >> 1, wc = w & 1;
    const int lr = lane & 15, lg = lane >> 4;
    const int m0 = blockIdx.y * 128, n0 = blockIdx.x * 128;
    f32x4 acc[4][4] = {};

    for (int k0 = 0; k0 < K; k0 += BK) {
        __syncthreads();
        for (int it = 0; it < 4; ++it) {
            int row = (tid >> 3) + it * 32;
            int kk = (tid & 7) * 4;
            short4 o;
            if (A_F32) {
                const float* A = (const float*)Ap;
                float4 t = *(const float4*)&A[(size_t)(m0 + row) * K + k0 + kk];
                o.x = f2bf(t.x); o.y = f2bf(t.y); o.z = f2bf(t.z); o.w = f2bf(t.w);
            } else {
                const short* A = (const short*)Ap;
                o = *(const short4*)&A[(size_t)(m0 + row) * K + k0 + kk];
            }
            *(short4*)&As[row * LDT + kk] = o;
        }
        for (int it = 0; it < 4; ++it) {
            int krow = (tid >> 5) + it * 8;
            int col = (tid & 31) * 4;
            float4 t = *(const float4*)&Bp[(size_t)(k0 + krow) * N + n0 + col];
            Bt[(col + 0) * LDT + krow] = f2bf(t.x);
            Bt[(col + 1) * LDT + krow] = f2bf(t.y);
            Bt[(col + 2) * LDT + krow] = f2bf(t.z);
            Bt[(col + 3) * LDT + krow] = f2bf(t.w);
        }
        __syncthreads();
        bf16x8 af[4], bfr[4];
        for (int rb = 0; rb < 4; ++rb)
            af[rb] = *(const bf16x8*)&As[(wr * 64 + rb * 16 + lr) * LDT + lg * 8];
        for (int cb = 0; cb < 4; ++cb)
            bfr[cb] = *(const bf16x8*)&Bt[(wc * 64 + cb * 16 + lr) * LDT + lg * 8];
        for (int rb = 0; rb < 4; ++rb)
            for (int cb = 0; cb < 4; ++cb)
                acc[rb][cb] = __builtin_amdgcn_mfma_f32_16x16x32_bf16(
                    af[rb], bfr[cb], acc[rb][cb], 0, 0, 0);
    }

    for (int rb = 0; rb < 4; ++rb)
        for (int cb = 0; cb < 4; ++cb)
            for (int j = 0; j < 4; ++j) {
                int row = m0 + wr * 64 + rb * 16 + lg * 4 + j;
                int col = n0 + wc * 64 + cb * 16 + lr;
                float v = acc[rb][cb][j];
                if (C_F32) ((float*)Cp)[(size_t)row * N + col] = v;
                else ((short*)Cp)[(size_t)row * N + col] = f2bf(v);
            }
}

// ---------------- RoPE in-place on bf16 Q and K; K also pre-scaled by 1/sqrt(hd) ----------------
__global__ __launch_bounds__(256)
void rope_kernel(short* __restrict__ Qp, int ldq, short* __restrict__ Kp, int ldk) {
    const int QP = BATCH * SEQ * NHEADS * 64;
    const int KP = BATCH * SEQ * NKV * 64;
    const int total = QP + KP;
    const float kscale = 0.08838834764831845f;  // 1/sqrt(128), folded into K
    for (int idx = blockIdx.x * blockDim.x + threadIdx.x; idx < total;
         idx += gridDim.x * blockDim.x) {
        short* base;
        size_t off;
        int i, row;
        float scl;
        if (idx < QP) {
            i = idx & 63;
            int hh = (idx >> 6) & (NHEADS - 1);
            row = idx >> 10;
            base = Qp;
            off = (size_t)row * ldq + hh * HD;
            scl = 1.0f;
        } else {
            int t = idx - QP;
            i = t & 63;
            int hh = (t >> 6) & (NKV - 1);
            row = t >> 8;
            base = Kp;
            off = (size_t)row * ldk + hh * HD;
            scl = kscale;
        }
        int pos = row & (SEQ - 1);
        float invf = exp2f(-(float)i * (13.287712379549449f / 64.0f));
        float ang = (float)pos * invf;
        float s, c;
        sincosf(ang, &s, &c);
        float t1 = bf2f(base[off + i]);
        float t2 = bf2f(base[off + i + 64]);
        base[off + i] = f2bf((t1 * c - t2 * s) * scl);
        base[off + i + 64] = f2bf((t2 * c + t1 * s) * scl);
    }
}

// ---------------- Flash attention: 8 waves, QBLK=256, paired q-tiles ----------------
// Block = 512 thr = 8 waves; wave w owns q-rows [q0+w*32, +32) as 2 groups of 16.
// LDS: Ks dbuf 32K + Vt 16K + Pw[8] 16K = 64K.  grid (4,16,4) = 256 blocks = 1/CU,
// 8 waves = 2 waves/SIMD (launch_bounds(512,2) caps regs at 256).
// K comes pre-scaled by 1/sqrt(hd) from rope_kernel.
__global__ __launch_bounds__(512, 2)
void attn_kernel(const short* __restrict__ Qp, int ldq,
                 const short* __restrict__ Kp, int ldk,
                 const short* __restrict__ Vp, int ldv,
                 short* __restrict__ O) {
    __shared__ short Ks[2][64 * 128];
    __shared__ short Vt[128 * 64];
    __shared__ short Pw[8][16 * 64];

    const int tid = threadIdx.x, lane = tid & 63, w = tid >> 6;
    const int lr = lane & 15, lg = lane >> 4;
    const int h = blockIdx.y, b = blockIdx.z;
    const int kvh = h >> 2;
    const size_t brow = (size_t)b * SEQ;

    const int d0 = (tid & 15) * 8;
    const int rvb = (tid >> 4) * 2;   // 0..62 even
    bf16x8 vreg[2];

#define STAGE_K(T, BUF)                                                              \
    {                                                                                \
        _Pragma("unroll") for (int it = 0; it < 2; ++it) {                           \
            int row = w * 8 + it * 4 + (lane >> 4);                                  \
            int cblk = (lane & 15) ^ (row & 7);                                      \
            gload16(&Kp[(brow + (size_t)(T) * 64 + row) * ldk + kvh * HD + cblk * 8],\
                    &Ks[BUF][(w * 8 + it * 4) * 128]);                               \
        }                                                                            \
    }
#define LOAD_V(T)                                                                    \
    {                                                                                \
        _Pragma("unroll") for (int h2 = 0; h2 < 2; ++h2)                             \
            vreg[h2] = *(const bf16x8*)&Vp[(brow + (size_t)(T) * 64 + rvb + h2) *    \
                                           ldv + kvh * HD + d0];                     \
    }
#define WRITE_V()                                                                    \
    {                                                                                \
        _Pragma("unroll") for (int e = 0; e < 8; ++e) {                              \
            int d = d0 + e;                                                          \
            int g = (e ^ lr) & 7;                                                    \
            unsigned int pk = ((unsigned int)(unsigned short)vreg[0][e]) |           \
                              (((unsigned int)(unsigned short)vreg[1][e]) << 16);    \
            *(unsigned int*)&Vt[d * 64 + (((rvb >> 3) ^ g) << 3) + (rvb & 7)] = pk;  \
        }                                                                            \
    }

    for (int pass = 0; pass < 2; ++pass) {
        const int qt = (pass == 0) ? (int)blockIdx.x : 7 - (int)blockIdx.x;
        const int q0 = qt * 256;
        const int qrow_g[2] = {q0 + w * 32 + lr, q0 + w * 32 + 16 + lr};

        bf16x8 qf[2][4];
#pragma unroll
        for (int g = 0; g < 2; ++g)
#pragma unroll
            for (int kc = 0; kc < 4; ++kc)
                qf[g][kc] = *(const bf16x8*)&Qp[(brow + qrow_g[g]) * ldq + h * HD +
                                                kc * 32 + lg * 8];

        f32x4 oacc[2][8] = {};
        float mrun[2] = {-__builtin_inff(), -__builtin_inff()};
        float lrun[2] = {0.f, 0.f};

        const int ntiles = 4 * qt + 4;

        // prologue (barrier protects Vt against previous pass's readers)
        STAGE_K(0, 0);
        LOAD_V(0);
        __syncthreads();
        WRITE_V();
        __syncthreads();

        int cur = 0;
        for (int t = 0; t < ntiles; ++t) {
            const int kv0 = t * 64;
            const int nxt = cur ^ 1;
            const bool pre = (t + 1 < ntiles);
            if (pre) {
                if (nxt) { STAGE_K(t + 1, 1); } else { STAGE_K(t + 1, 0); }
                LOAD_V(t + 1);
            }

#pragma unroll
            for (int g = 0; g < 2; ++g) {
                const int qrow = qrow_g[g];
                // QK^T swapped: sacc[cb][j] = S^T[k=kv0+cb*16+lg*4+j][q=lr]
                f32x4 sacc[4] = {};
                __builtin_amdgcn_s_setprio(1);
#pragma unroll
                for (int cb = 0; cb < 4; ++cb)
#pragma unroll
                    for (int kc = 0; kc < 4; ++kc) {
                        bf16x8 kf = *(const bf16x8*)&Ks[cur][(cb * 16 + lr) * 128 +
                                                             (((kc * 4 + lg) ^ (lr & 7)) << 3)];
                        sacc[cb] = __builtin_amdgcn_mfma_f32_16x16x32_bf16(
                            kf, qf[g][kc], sacc[cb], 0, 0, 0);
                    }
                __builtin_amdgcn_s_setprio(0);

                float st[16];
                const bool need_mask = (kv0 + 63 > qrow);
#pragma unroll
                for (int cb = 0; cb < 4; ++cb)
#pragma unroll
                    for (int j = 0; j < 4; ++j) {
                        float s = sacc[cb][j];
                        if (need_mask) {
                            int col = kv0 + cb * 16 + lg * 4 + j;
                            if (col > qrow) s = -__builtin_inff();
                        }
                        st[cb * 4 + j] = s;
                    }
                float m8[8], m4[4];
#pragma unroll
                for (int i = 0; i < 8; ++i) m8[i] = fmaxf(st[i], st[i + 8]);
#pragma unroll
                for (int i = 0; i < 4; ++i) m4[i] = fmaxf(m8[i], m8[i + 4]);
                float rowmax = fmaxf(fmaxf(m4[0], m4[1]), fmaxf(m4[2], m4[3]));
                rowmax = fmaxf(rowmax, __shfl_xor(rowmax, 16, 64));
                rowmax = fmaxf(rowmax, __shfl_xor(rowmax, 32, 64));

                // defer-max (T13): skip rescale when growth <= 8
                if (!__all(rowmax <= mrun[g] + 8.f)) {
                    float mnew = fmaxf(mrun[g], rowmax);
                    float alpha = __expf(mrun[g] - mnew);
                    lrun[g] *= alpha;
#pragma unroll
                    for (int db = 0; db < 8; ++db) {
                        f32x4 o = oacc[g][db];
#pragma unroll
                        for (int j = 0; j < 4; ++j) o[j] *= alpha;
                        oacc[g][db] = o;
                    }
                    mrun[g] = mnew;
                }
                const float mbase = mrun[g];
#pragma unroll
                for (int i = 0; i < 16; ++i) st[i] = __expf(st[i] - mbase);
                float s8[8], s4[4];
#pragma unroll
                for (int i = 0; i < 8; ++i) s8[i] = st[i] + st[i + 8];
#pragma unroll
                for (int i = 0; i < 4; ++i) s4[i] = s8[i] + s8[i + 4];
                float rs = (s4[0] + s4[1]) + (s4[2] + s4[3]);
                rs += __shfl_xor(rs, 16, 64);
                rs += __shfl_xor(rs, 32, 64);
                lrun[g] += rs;

                // P^T -> per-wave LDS via v_cvt_pk_bf16_f32 (8B stores)
#pragma unroll
                for (int cb = 0; cb < 4; ++cb) {
                    uint2 pk2;
                    pk2.x = cvtpk_bf16(st[cb * 4 + 0], st[cb * 4 + 1]);
                    pk2.y = cvtpk_bf16(st[cb * 4 + 2], st[cb * 4 + 3]);
                    int chunk = (cb * 2 + (lg >> 1)) ^ (lr & 7);
                    *(uint2*)&Pw[w][lr * 64 + (chunk << 3) + (lg & 1) * 4] = pk2;
                }
                bf16x8 pf[2];
#pragma unroll
                for (int kc = 0; kc < 2; ++kc)
                    pf[kc] = *(const bf16x8*)&Pw[w][lr * 64 +
                                                   (((kc * 4 + lg) ^ (lr & 7)) << 3)];

                // PV: oacc[g] accumulates O^T[d][q=lr]
                __builtin_amdgcn_s_setprio(1);
#pragma unroll
                for (int db = 0; db < 8; ++db)
#pragma unroll
                    for (int kc = 0; kc < 2; ++kc) {
                        int d = db * 16 + lr;
                        int gg = ((lr & 7) ^ (db * 2 + (lr >> 3))) & 7;
                        bf16x8 vf = *(const bf16x8*)&Vt[d * 64 + (((kc * 4 + lg) ^ gg) << 3)];
                        oacc[g][db] = __builtin_amdgcn_mfma_f32_16x16x32_bf16(
                            vf, pf[kc], oacc[g][db], 0, 0, 0);
                    }
                __builtin_amdgcn_s_setprio(0);
            }

            if (pre) {
                __syncthreads();   // all PV reads of Vt done; K(t+1) gloads drained
                WRITE_V();
                __syncthreads();   // Vt(t+1) + Ks[nxt] visible
                cur = nxt;
            }
        }

        // epilogue: O[qrow_g][d], d = db*16+lg*4+j
#pragma unroll
        for (int g = 0; g < 2; ++g) {
            const float invl = 1.0f / lrun[g];
#pragma unroll
            for (int db = 0; db < 8; ++db) {
                short4 o4;
                o4.x = f2bf(oacc[g][db][0] * invl);
                o4.y = f2bf(oacc[g][db][1] * invl);
                o4.z = f2bf(oacc[g][db][2] * invl);
                o4.w = f2bf(oacc[g][db][3] * invl);
                *(short4*)&O[(brow + qrow_g[g]) * DMODEL + h * HD + db * 16 + lg * 4] = o4;
            }
        }
    }
#undef STAGE_K
#undef LOAD_V
#undef WRITE_V
}

extern "C" void kernel_launch(void* const* d_in, const int* in_sizes, int n_in,
                              void* d_out, int out_size, void* d_ws, size_t ws_size,
                              hipStream_t stream) {
    const float* x = (const float*)d_in[0];
    const float* Wq = (const float*)d_in[1];
    const float* Wk = (const float*)d_in[2];
    const float* Wv = (const float*)d_in[3];
    const float* Wo = (const float*)d_in[4];
    float* out = (float*)d_out;

    const size_t BS = (size_t)BATCH * SEQ;  // 8192
    dim3 blk(256);

    const size_t planA_shorts = BS * 2048 + BS * 3072 + (size_t)3072 * 2048 + (size_t)2048 * 2048;
    if (ws_size >= planA_shorts * 2) {
        short* xb = (short*)d_ws;                    // [8192][2048] bf16 (reused as AO)
        short* QKV = xb + BS * 2048;                 // [8192][3072]: Q | K | V
        short* WqkvT = QKV + BS * 3072;              // [3072][2048]
        short* WoT = WqkvT + (size_t)3072 * 2048;    // [2048][2048]
        short* AO = xb;

        conv_x<<<dim3(2048), blk, 0, stream>>>(x, xb, (int)(BS * 2048 / 8));
        tkern<<<dim3(32, 32), blk, 0, stream>>>(Wq, WqkvT, 2048, 2048);
        tkern<<<dim3(8, 32), blk, 0, stream>>>(Wk, WqkvT + (size_t)2048 * 2048, 2048, 512);
        tkern<<<dim3(8, 32), blk, 0, stream>>>(Wv, WqkvT + (size_t)2560 * 2048, 2048, 512);
        tkern<<<dim3(32, 32), blk, 0, stream>>>(Wo, WoT, 2048, 2048);
        gemm_bt<false><<<dim3(24, 64), blk, 0, stream>>>(xb, WqkvT, (void*)QKV, 8192, 3072, 2048);
        rope_kernel<<<dim3(4096), blk, 0, stream>>>(QKV, 3072, QKV + 2048, 3072);
        attn_kernel<<<dim3(4, NHEADS, BATCH), dim3(512), 0, stream>>>(
            QKV, 3072, QKV + 2048, 3072, QKV + 2560, 3072, AO);
        gemm_bt<true><<<dim3(16, 64), blk, 0, stream>>>(AO, WoT, (void*)out, 8192, 2048, 2048);
    } else {
        short* Qb = (short*)d_ws;
        short* Kb = Qb + BS * DMODEL;
        short* Vb = Kb + BS * (NKV * HD);
        short* AO = Vb + BS * (NKV * HD);
        gemm_kernel<true, false><<<dim3(16, 64), blk, 0, stream>>>((const void*)x, Wq, (void*)Qb, 8192, 2048, 2048);
        gemm_kernel<true, false><<<dim3(4, 64), blk, 0, stream>>>((const void*)x, Wk, (void*)Kb, 8192, 512, 2048);
        gemm_kernel<true, false><<<dim3(4, 64), blk, 0, stream>>>((const void*)x, Wv, (void*)Vb, 8192, 512, 2048);
        rope_kernel<<<dim3(4096), blk, 0, stream>>>(Qb, 2048, Kb, 512);
        attn_kernel<<<dim3(4, NHEADS, BATCH), dim3(512), 0, stream>>>(
            Qb, 2048, Kb, 512, Vb, 512, AO);
        gemm_kernel<false, true><<<dim3(16, 64), blk, 0, stream>>>((const void*)AO, Wo, (void*)out, 8192, 2048, 2048);
    }
}